// Round 8
// baseline (177.635 us; speedup 1.0000x reference)
//
#include <hip/hip_runtime.h>

#define B_  2
#define S_  2048
#define E_  1024
#define H_  16
#define D_  64
#define NGLOB 2
#define NRAND 3
#define WIN 3

typedef __bf16 bf16x8 __attribute__((ext_vector_type(8)));
typedef float  f32x4  __attribute__((ext_vector_type(4)));

__device__ __forceinline__ unsigned short f2bf(float f) {
    unsigned u = __builtin_bit_cast(unsigned, f);
    unsigned r = u + 0x7FFFu + ((u >> 16) & 1u);   // RNE
    return (unsigned short)(r >> 16);
}
__device__ __forceinline__ float bf2f(unsigned short u) {
    return __builtin_bit_cast(float, (unsigned)u << 16);
}

// async global->LDS 16B DMA. LDS dest is wave-uniform base + lane*16.
__device__ __forceinline__ void g2l16(const unsigned short* g, unsigned short* l) {
    __builtin_amdgcn_global_load_lds(
        (const __attribute__((address_space(1))) unsigned*)g,
        (__attribute__((address_space(3))) unsigned*)l, 16, 0, 0);
}

// ---------------- fused fp32 -> bf16 conversion for x + 4 weights ----------------
__global__ __launch_bounds__(256)
void convert_all(const float* __restrict__ x,  const float* __restrict__ qw,
                 const float* __restrict__ kw, const float* __restrict__ vw,
                 const float* __restrict__ ow,
                 unsigned short* __restrict__ xb, unsigned short* __restrict__ wqkv,
                 unsigned short* __restrict__ wo) {
    const int XN = (B_ * S_ * E_) / 4;      // 1048576
    const int WN = (E_ * E_) / 4;           // 262144
    int i = blockIdx.x * blockDim.x + threadIdx.x;
    int r, loc;
    if (i < XN) { r = 0; loc = i; }
    else        { int j = i - XN; r = 1 + (j >> 18); loc = j & (WN - 1); }
    const float* src = r == 0 ? x : r == 1 ? qw : r == 2 ? kw : r == 3 ? vw : ow;
    float4 f = ((const float4*)src)[loc];
    ushort4 u;
    u.x = f2bf(f.x); u.y = f2bf(f.y); u.z = f2bf(f.z); u.w = f2bf(f.w);
    ushort4* dst = r == 0 ? (ushort4*)xb : r == 4 ? (ushort4*)wo
                 : (ushort4*)wqkv + (size_t)(r - 1) * WN;
    dst[loc] = u;
}

// ---------------- QKV GEMM: 256x256 tile, BK=64, 8-phase counted-vmcnt ------------
// R8 = R1's 8-phase schedule + rule-#18 fix: sched_barrier(0) after every inline
// lgkmcnt(0) (hipcc otherwise hoists reg-only MFMA past the wait, scrambling the
// phase schedule). Deepest legal prefetch at 2-dbuf: B staged 6-7 phases ahead,
// A 3-4; vmcnt(4) at tile end waits only on loads >=2.2 phases old (~L2 lat).
__device__ __forceinline__ void stage_half(const unsigned short* g, unsigned short* l,
                                           int t, int wave, int K) {
    #pragma unroll
    for (int j = 0; j < 2; ++j) {
        int c = j * 512 + t;
        int row = c >> 3, cc = c & 7;
        g2l16(g + (size_t)row * K + ((cc ^ (row & 7)) << 3), l + j * 4096 + wave * 512);
    }
}
__device__ __forceinline__ bf16x8 ldfrag(const unsigned short* r, int row, int kc) {
    return *(const bf16x8*)&r[row * 64 + ((kc ^ (row & 7)) << 3)];
}

__global__ __launch_bounds__(512, 2)
void gemm_qkv(const unsigned short* __restrict__ A,  // [M][K] bf16
              const unsigned short* __restrict__ W,  // [N][K] bf16
              const float* __restrict__ bi0, const float* __restrict__ bi1,
              const float* __restrict__ bi2,
              unsigned short* __restrict__ Cb, int M, int N, int K) {
    __shared__ unsigned short lds[2][4][128 * 64];   // 128 KB
    const int t = threadIdx.x;
    const int lane = t & 63;
    const int wave = t >> 6;          // 0..7
    const int wr = wave >> 2;         // 0..1  M-half
    const int wc = wave & 3;          // 0..3  N-quarter
    const int lq = lane >> 4;
    const int lr = lane & 15;
    const int bm = blockIdx.x * 256;
    const int bn = blockIdx.y * 256;
    const int nt = K >> 6;            // 16

    const unsigned short* Ab = A + (size_t)bm * K;
    const unsigned short* Wb = W + (size_t)bn * K;

    f32x4 acc[8][4] = {};

    // prologue: tile0 {A0,A1,B0,B1}, tile1 {B0,B1}. vmcnt(4) -> tile0 complete.
    stage_half(Ab,                         &lds[0][0][0], t, wave, K);
    stage_half(Ab + (size_t)128 * K,       &lds[0][1][0], t, wave, K);
    stage_half(Wb,                         &lds[0][2][0], t, wave, K);
    stage_half(Wb + (size_t)128 * K,       &lds[0][3][0], t, wave, K);
    stage_half(Wb + 64,                    &lds[1][2][0], t, wave, K);
    stage_half(Wb + (size_t)128 * K + 64,  &lds[1][3][0], t, wave, K);
    asm volatile("s_waitcnt vmcnt(4)" ::: "memory");
    __builtin_amdgcn_s_barrier();

    #pragma unroll 2
    for (int kt = 0; kt < nt; ++kt) {
        const int cur = kt & 1;
        const unsigned short* rA = &lds[cur][wr][0];
        const unsigned short* rB = &lds[cur][2 + (wc >> 1)][0];
        const int brow = (wc & 1) * 64;
        bf16x8 af[2][2], bfr[4][2];

        // ---- phase 0: read A m0-1 + B n0-3 (12); stage (kt+1).A0
        #pragma unroll
        for (int m = 0; m < 2; ++m)
            #pragma unroll
            for (int ks = 0; ks < 2; ++ks)
                af[m][ks] = ldfrag(rA, m * 16 + lr, ks * 4 + lq);
        #pragma unroll
        for (int n = 0; n < 4; ++n)
            #pragma unroll
            for (int ks = 0; ks < 2; ++ks)
                bfr[n][ks] = ldfrag(rB, brow + n * 16 + lr, ks * 4 + lq);
        if (kt + 1 < nt)
            stage_half(Ab + (size_t)(kt + 1) * 64, &lds[cur ^ 1][0][0], t, wave, K);
        __builtin_amdgcn_s_barrier();
        asm volatile("s_waitcnt lgkmcnt(0)" ::: "memory");
        __builtin_amdgcn_sched_barrier(0);
        __builtin_amdgcn_s_setprio(1);
        #pragma unroll
        for (int m = 0; m < 2; ++m)
            #pragma unroll
            for (int n = 0; n < 4; ++n)
                #pragma unroll
                for (int ks = 0; ks < 2; ++ks)
                    acc[m][n] = __builtin_amdgcn_mfma_f32_16x16x32_bf16(af[m][ks], bfr[n][ks], acc[m][n], 0, 0, 0);
        __builtin_amdgcn_s_setprio(0);
        __builtin_amdgcn_s_barrier();

        // ---- phase 1: read A m2-3; stage (kt+1).A1, (kt+2).B0
        #pragma unroll
        for (int m = 0; m < 2; ++m)
            #pragma unroll
            for (int ks = 0; ks < 2; ++ks)
                af[m][ks] = ldfrag(rA, (2 + m) * 16 + lr, ks * 4 + lq);
        if (kt + 1 < nt)
            stage_half(Ab + (size_t)128 * K + (size_t)(kt + 1) * 64, &lds[cur ^ 1][1][0], t, wave, K);
        if (kt + 2 < nt)
            stage_half(Wb + (size_t)(kt + 2) * 64, &lds[cur][2][0], t, wave, K);
        __builtin_amdgcn_s_barrier();
        asm volatile("s_waitcnt lgkmcnt(0)" ::: "memory");
        __builtin_amdgcn_sched_barrier(0);
        __builtin_amdgcn_s_setprio(1);
        #pragma unroll
        for (int m = 0; m < 2; ++m)
            #pragma unroll
            for (int n = 0; n < 4; ++n)
                #pragma unroll
                for (int ks = 0; ks < 2; ++ks)
                    acc[2 + m][n] = __builtin_amdgcn_mfma_f32_16x16x32_bf16(af[m][ks], bfr[n][ks], acc[2 + m][n], 0, 0, 0);
        __builtin_amdgcn_s_setprio(0);
        __builtin_amdgcn_s_barrier();

        // ---- phase 2: read A m4-5; stage (kt+2).B1
        #pragma unroll
        for (int m = 0; m < 2; ++m)
            #pragma unroll
            for (int ks = 0; ks < 2; ++ks)
                af[m][ks] = ldfrag(rA, (4 + m) * 16 + lr, ks * 4 + lq);
        if (kt + 2 < nt)
            stage_half(Wb + (size_t)128 * K + (size_t)(kt + 2) * 64, &lds[cur][3][0], t, wave, K);
        __builtin_amdgcn_s_barrier();
        asm volatile("s_waitcnt lgkmcnt(0)" ::: "memory");
        __builtin_amdgcn_sched_barrier(0);
        __builtin_amdgcn_s_setprio(1);
        #pragma unroll
        for (int m = 0; m < 2; ++m)
            #pragma unroll
            for (int n = 0; n < 4; ++n)
                #pragma unroll
                for (int ks = 0; ks < 2; ++ks)
                    acc[4 + m][n] = __builtin_amdgcn_mfma_f32_16x16x32_bf16(af[m][ks], bfr[n][ks], acc[4 + m][n], 0, 0, 0);
        __builtin_amdgcn_s_setprio(0);
        __builtin_amdgcn_s_barrier();

        // ---- phase 3: read A m6-7; no stage; counted vmcnt at tile end
        #pragma unroll
        for (int m = 0; m < 2; ++m)
            #pragma unroll
            for (int ks = 0; ks < 2; ++ks)
                af[m][ks] = ldfrag(rA, (6 + m) * 16 + lr, ks * 4 + lq);
        __builtin_amdgcn_s_barrier();
        asm volatile("s_waitcnt lgkmcnt(0)" ::: "memory");
        __builtin_amdgcn_sched_barrier(0);
        __builtin_amdgcn_s_setprio(1);
        #pragma unroll
        for (int m = 0; m < 2; ++m)
            #pragma unroll
            for (int n = 0; n < 4; ++n)
                #pragma unroll
                for (int ks = 0; ks < 2; ++ks)
                    acc[6 + m][n] = __builtin_amdgcn_mfma_f32_16x16x32_bf16(af[m][ks], bfr[n][ks], acc[6 + m][n], 0, 0, 0);
        __builtin_amdgcn_s_setprio(0);
        if (kt + 2 < nt) asm volatile("s_waitcnt vmcnt(4)" ::: "memory");
        else             asm volatile("s_waitcnt vmcnt(0)" ::: "memory");
        __builtin_amdgcn_s_barrier();
    }

    #pragma unroll
    for (int m = 0; m < 8; ++m) {
        int row0 = bm + wr * 128 + m * 16 + lq * 4;
        #pragma unroll
        for (int n = 0; n < 4; ++n) {
            int col = bn + wc * 64 + n * 16 + lr;
            const float* bp = col < E_ ? bi0 : (col < 2 * E_ ? bi1 : bi2);
            float bv = bp[col & (E_ - 1)];
            #pragma unroll
            for (int r = 0; r < 4; ++r)
                Cb[(size_t)(row0 + r) * N + col] = f2bf(acc[m][n][r] + bv);
        }
    }
}

// ---------------- O GEMM: 128x128 tile, fp32 out, XCD-swizzled ----------------
__global__ __launch_bounds__(256, 3)
void gemm_o(const unsigned short* __restrict__ A,   // [M][K] bf16 (attn)
            const unsigned short* __restrict__ W,   // [N][K] bf16 (wo)
            const float* __restrict__ bias,
            float* __restrict__ Cf, int M, int N, int K) {
    __shared__ unsigned short sA[128 * 64];   // 16 KB
    __shared__ unsigned short sB[128 * 64];   // 16 KB
    const int nwg = gridDim.x;                // 256
    const int id  = (blockIdx.x & 7) * (nwg >> 3) + (blockIdx.x >> 3);
    const int bm = (id & 31) * 128;           // M/128 = 32
    const int bn = (id >> 5) * 128;
    const int t = threadIdx.x;
    const int lane = t & 63;
    const int wave = t >> 6;
    const int wm = wave >> 1, wn = wave & 1;
    const int lq = lane >> 4;
    const int lr = lane & 15;

    f32x4 acc[4][4] = {};

    for (int k0 = 0; k0 < K; k0 += 64) {
        const unsigned short* Abase = A + (size_t)bm * K + k0;
        const unsigned short* Wbase = W + (size_t)bn * K + k0;
        #pragma unroll
        for (int j = 0; j < 4; ++j) {
            int c = j * 256 + t;
            int row = c >> 3, cc = c & 7;
            int gcol = ((cc ^ (row & 7)) << 3);
            int dst = j * 2048 + wave * 512;
            g2l16(Abase + (size_t)row * K + gcol, sA + dst);
            g2l16(Wbase + (size_t)row * K + gcol, sB + dst);
        }
        __syncthreads();

        #pragma unroll
        for (int ks = 0; ks < 2; ++ks) {
            const int sw = (((ks << 2) + lq) ^ (lr & 7)) << 3;
            bf16x8 af[4], bfr[4];
            #pragma unroll
            for (int i = 0; i < 4; ++i)
                af[i] = *(const bf16x8*)&sA[(wm * 64 + i * 16 + lr) * 64 + sw];
            #pragma unroll
            for (int j = 0; j < 4; ++j)
                bfr[j] = *(const bf16x8*)&sB[(wn * 64 + j * 16 + lr) * 64 + sw];
            #pragma unroll
            for (int i = 0; i < 4; ++i)
                #pragma unroll
                for (int j = 0; j < 4; ++j)
                    acc[i][j] = __builtin_amdgcn_mfma_f32_16x16x32_bf16(af[i], bfr[j], acc[i][j], 0, 0, 0);
        }
        __syncthreads();
    }

    #pragma unroll
    for (int i = 0; i < 4; ++i) {
        int row0 = bm + wm * 64 + i * 16 + lq * 4;
        #pragma unroll
        for (int j = 0; j < 4; ++j) {
            int col = bn + wn * 64 + j * 16 + lr;
            float bv = bias[col];
            #pragma unroll
            for (int r = 0; r < 4; ++r)
                Cf[(size_t)(row0 + r) * N + col] = acc[i][j][r] + bv;
        }
    }
}

// ---------------- fused: row-streaming global path + sparse rows -----------------
__global__ __launch_bounds__(256, 5)
void attn_fused(const unsigned short* __restrict__ qkv,
                const int* __restrict__ rnd,
                float* __restrict__ gaccp, float* __restrict__ gms,
                unsigned short* __restrict__ attn) {
    const int NB = B_ * (S_ - 2);     // 4092
    int t = threadIdx.x;

    if (blockIdx.x < 256) {
        // ---- one (b, 16-key chunk) per block; all heads, both global queries ----
        int g = blockIdx.x;
        int b = g >> 7, ck = g & 127;
        int w = t >> 6, l = t & 63;
        int h = l >> 2, dseg = l & 3;          // head, dim-quarter (16 dims/lane)
        int key0 = ck * 16 + w * 4;            // this wave's 4 keys

        __shared__ float sm[4][16][4];         // [wave][head][m0,sum0,m1,sum1]
        __shared__ float ovv[4][2][16][68];    // [wave][i][head][dim(+pad)] ~34.8KB

        // Q for both global rows, this lane's 16 dims
        const unsigned short* qb0 = qkv + (size_t)(b * S_) * 3072 + h * 64 + dseg * 16;
        const unsigned short* qb1 = qb0 + 3072;
        bf16x8 q0a = *(const bf16x8*)qb0, q0b = *(const bf16x8*)(qb0 + 8);
        bf16x8 q1a = *(const bf16x8*)qb1, q1b = *(const bf16x8*)(qb1 + 8);

        // phase 1: K for 4 keys + V for keys 0,1
        const unsigned short* kr0 =
            qkv + (size_t)(b * S_ + key0) * 3072 + E_ + h * 64 + dseg * 16;
        bf16x8 ka[4], kb[4];
        #pragma unroll
        for (int j = 0; j < 4; ++j) {
            ka[j] = *(const bf16x8*)(kr0 + (size_t)j * 3072);
            kb[j] = *(const bf16x8*)(kr0 + (size_t)j * 3072 + 8);
        }
        bf16x8 va0 = *(const bf16x8*)(kr0 + E_);
        bf16x8 vb0 = *(const bf16x8*)(kr0 + E_ + 8);
        bf16x8 va1 = *(const bf16x8*)(kr0 + 3072 + E_);
        bf16x8 vb1 = *(const bf16x8*)(kr0 + 3072 + E_ + 8);

        // scores for both queries, 4 keys (4-lane dot + 2-level shfl)
        float s0[4], s1[4];
        #pragma unroll
        for (int j = 0; j < 4; ++j) {
            float a0 = 0.f, a1 = 0.f;
            #pragma unroll
            for (int e = 0; e < 8; ++e) {
                float k1 = (float)ka[j][e], k2 = (float)kb[j][e];
                a0 += (float)q0a[e] * k1 + (float)q0b[e] * k2;
                a1 += (float)q1a[e] * k1 + (float)q1b[e] * k2;
            }
            a0 += __shfl_xor(a0, 1); a0 += __shfl_xor(a0, 2);
            a1 += __shfl_xor(a1, 1); a1 += __shfl_xor(a1, 2);
            s0[j] = a0 * 0.125f; s1[j] = a1 * 0.125f;
        }

        // wave-local flash partials over 4 keys
        float m0 = fmaxf(fmaxf(s0[0], s0[1]), fmaxf(s0[2], s0[3]));
        float m1 = fmaxf(fmaxf(s1[0], s1[1]), fmaxf(s1[2], s1[3]));
        float e0[4], e1[4], sum0 = 0.f, sum1 = 0.f;
        #pragma unroll
        for (int j = 0; j < 4; ++j) {
            e0[j] = __expf(s0[j] - m0); sum0 += e0[j];
            e1[j] = __expf(s1[j] - m1); sum1 += e1[j];
        }

        // phase 2: PV keys 0,1; V keys 2,3 load in parallel
        bf16x8 va2 = *(const bf16x8*)(kr0 + 2 * 3072 + E_);
        bf16x8 vb2 = *(const bf16x8*)(kr0 + 2 * 3072 + E_ + 8);
        bf16x8 va3 = *(const bf16x8*)(kr0 + 3 * 3072 + E_);
        bf16x8 vb3 = *(const bf16x8*)(kr0 + 3 * 3072 + E_ + 8);

        float o0[16] = {}, o1[16] = {};
        #pragma unroll
        for (int e = 0; e < 8; ++e) {
            float v1 = (float)va0[e], v2 = (float)vb0[e];
            float v3 = (float)va1[e], v4 = (float)vb1[e];
            o0[e]     += e0[0] * v1 + e0[1] * v3;
            o0[8 + e] += e0[0] * v2 + e0[1] * v4;
            o1[e]     += e1[0] * v1 + e1[1] * v3;
            o1[8 + e] += e1[0] * v2 + e1[1] * v4;
        }
        #pragma unroll
        for (int e = 0; e < 8; ++e) {
            float v1 = (float)va2[e], v2 = (float)vb2[e];
            float v3 = (float)va3[e], v4 = (float)vb3[e];
            o0[e]     += e0[2] * v1 + e0[3] * v3;
            o0[8 + e] += e0[2] * v2 + e0[3] * v4;
            o1[e]     += e1[2] * v1 + e1[3] * v3;
            o1[8 + e] += e1[2] * v2 + e1[3] * v4;
        }

        if (dseg == 0) {
            sm[w][h][0] = m0; sm[w][h][1] = sum0;
            sm[w][h][2] = m1; sm[w][h][3] = sum1;
        }
        #pragma unroll
        for (int e = 0; e < 16; ++e) {
            ovv[w][0][h][dseg * 16 + e] = o0[e];
            ovv[w][1][h][dseg * 16 + e] = o1[e];
        }
        __syncthreads();

        // combine 4 waves -> per-chunk partial; thread handles 8 of 2048 outputs
        #pragma unroll
        for (int r = 0; r < 8; ++r) {
            int ot = r * 256 + t;                       // i*1024 + h*64 + d
            int ii = ot >> 10, hh = (ot >> 6) & 15, d = ot & 63;
            float M = -1e30f;
            #pragma unroll
            for (int ww = 0; ww < 4; ++ww) M = fmaxf(M, sm[ww][hh][ii * 2]);
            float den = 0.f, num = 0.f;
            #pragma unroll
            for (int ww = 0; ww < 4; ++ww) {
                float f = __expf(sm[ww][hh][ii * 2] - M);
                den += sm[ww][hh][ii * 2 + 1] * f;
                num += ovv[ww][ii][hh][d] * f;
            }
            int tup = b * 32 + ii * 16 + hh;
            gaccp[((size_t)tup * 128 + ck) * D_ + d] = num;
            if (d == 0) {
                gms[((size_t)tup * 128 + ck) * 2]     = M;
                gms[((size_t)tup * 128 + ck) * 2 + 1] = den;
            }
        }
        return;
    }

    // ---- sparse rows: one wave per row ----
    int bb = blockIdx.x - 256;                        // [0,1024)
    int bidx = (bb & 7) * 128 + (bb >> 3);            // XCD swizzle
    int w = t >> 6, l = t & 63;
    int row = bidx * 4 + w;
    bool valid = row < NB;
    int b = row / (S_ - 2);
    int i = row % (S_ - 2) + 2;
    if (!valid) { b = 0; i = 2; }

    __shared__ int   cols_s[4][12];
    __shared__ int   ncol_sh[4];
    __shared__ float pr_s[4][16 * 13 + 3];

    const bf16x8* qp = (const bf16x8*)(qkv + (size_t)(b * S_ + i) * 3072);
    bf16x8 q0 = qp[l * 2], q1 = qp[l * 2 + 1];
    float qreg[16];
    #pragma unroll
    for (int j = 0; j < 8; ++j) { qreg[j] = (float)q0[j]; qreg[8 + j] = (float)q1[j]; }

    if (l == 0) {
        int* cols = cols_s[w];
        int n = 0;
        cols[n++] = 0; cols[n++] = 1;
        int lo = i - WIN; if (lo < NGLOB) lo = NGLOB;
        int hi = i + WIN; if (hi > S_ - 1) hi = S_ - 1;
        for (int j = lo; j <= hi; ++j) cols[n++] = j;
        for (int r = 0; r < NRAND; ++r) {
            int c = rnd[i * NRAND + r];
            bool dup = false;
            for (int q = 0; q < n; ++q) dup = dup || (cols[q] == c);
            if (!dup) cols[n++] = c;
        }
        ncol_sh[w] = n;
        for (int q = n; q < 12; ++q) cols[q] = 0;
    }
    __syncthreads();
    const int n = ncol_sh[w];
    const int h4 = l >> 2;

    float sco[12];
    #pragma unroll
    for (int c = 0; c < 12; ++c) {
        const bf16x8* kp = (const bf16x8*)(qkv + (size_t)(b * S_ + cols_s[w][c]) * 3072 + E_);
        bf16x8 k0 = kp[l * 2], k1 = kp[l * 2 + 1];
        float s = 0.f;
        #pragma unroll
        for (int j = 0; j < 8; ++j) s += qreg[j] * (float)k0[j] + qreg[8 + j] * (float)k1[j];
        s += __shfl_xor(s, 1);
        s += __shfl_xor(s, 2);
        sco[c] = (c < n) ? s * 0.125f : -1e30f;
    }

    if ((l & 3) == 0) {
        float m = -1e30f;
        #pragma unroll
        for (int c = 0; c < 12; ++c) m = fmaxf(m, sco[c]);
        float sum = 0.f;
        #pragma unroll
        for (int c = 0; c < 12; ++c) { float e = __expf(sco[c] - m); sco[c] = e; sum += e; }
        float inv = 1.f / sum;
        #pragma unroll
        for (int c = 0; c < 12; ++c) pr_s[w][h4 * 13 + c] = sco[c] * inv;
    }
    __syncthreads();

    float o[16] = {};
    #pragma unroll
    for (int c = 0; c < 12; ++c) {
        float p = pr_s[w][h4 * 13 + c];
        const bf16x8* vp = (const bf16x8*)(qkv + (size_t)(b * S_ + cols_s[w][c]) * 3072 + 2 * E_);
        bf16x8 v0 = vp[l * 2], v1 = vp[l * 2 + 1];
        #pragma unroll
        for (int j = 0; j < 8; ++j) { o[j] += p * (float)v0[j]; o[8 + j] += p * (float)v1[j]; }
    }

    if (valid) {
        ushort4 u0, u1, u2, u3;
        u0.x = f2bf(o[0]);  u0.y = f2bf(o[1]);  u0.z = f2bf(o[2]);  u0.w = f2bf(o[3]);
        u1.x = f2bf(o[4]);  u1.y = f2bf(o[5]);  u1.z = f2bf(o[6]);  u1.w = f2bf(o[7]);
        u2.x = f2bf(o[8]);  u2.y = f2bf(o[9]);  u2.z = f2bf(o[10]); u2.w = f2bf(o[11]);
        u3.x = f2bf(o[12]); u3.y = f2bf(o[13]); u3.z = f2bf(o[14]); u3.w = f2bf(o[15]);
        ushort4* op = (ushort4*)(attn + (size_t)(b * S_ + i) * E_ + l * 16);
        op[0] = u0; op[1] = u1; op[2] = u2; op[3] = u3;
    }
}

// merge 128 chunk partials per tuple (64 blocks, 4-way chunk split + LDS combine)
__global__ __launch_bounds__(256)
void gattn_fin(const float* __restrict__ gaccp, const float* __restrict__ gms,
               unsigned short* __restrict__ attn) {
    int tup = blockIdx.x;                       // 64
    int b = tup >> 5, i = (tup >> 4) & 1, h = tup & 15;
    int t = threadIdx.x, g = t >> 6, d = t & 63;
    __shared__ float sM[4], sD[4], sO[4][D_];

    float M = -1e30f;
    #pragma unroll 8
    for (int c = g * 32; c < g * 32 + 32; ++c)
        M = fmaxf(M, gms[((size_t)tup * 128 + c) * 2]);
    float den = 0.f, num = 0.f;
    #pragma unroll 8
    for (int c = g * 32; c < g * 32 + 32; ++c) {
        float f = __expf(gms[((size_t)tup * 128 + c) * 2] - M);
        den += gms[((size_t)tup * 128 + c) * 2 + 1] * f;
        num += gaccp[((size_t)tup * 128 + c) * D_ + d] * f;
    }
    if (d == 0) { sM[g] = M; sD[g] = den; }
    sO[g][d] = num;
    __syncthreads();
    if (g == 0) {
        float MM = fmaxf(fmaxf(sM[0], sM[1]), fmaxf(sM[2], sM[3]));
        float dd = 0.f, nn = 0.f;
        #pragma unroll
        for (int j = 0; j < 4; ++j) {
            float f = __expf(sM[j] - MM);
            dd += sD[j] * f;
            nn += sO[j][d] * f;
        }
        attn[(size_t)(b * S_ + i) * E_ + h * D_ + d] = f2bf(nn / dd);
    }
}

extern "C" void kernel_launch(void* const* d_in, const int* in_sizes, int n_in,
                              void* d_out, int out_size, void* d_ws, size_t ws_size,
                              hipStream_t stream) {
    const float* x   = (const float*)d_in[0];
    const int*   rnd = (const int*)d_in[1];
    const float* qw  = (const float*)d_in[2];
    const float* qb  = (const float*)d_in[3];
    const float* kw  = (const float*)d_in[4];
    const float* kb  = (const float*)d_in[5];
    const float* vw  = (const float*)d_in[6];
    const float* vb  = (const float*)d_in[7];
    const float* ow  = (const float*)d_in[8];
    const float* ob  = (const float*)d_in[9];
    float* out = (float*)d_out;

    char* ws = (char*)d_ws;
    unsigned short* xb    = (unsigned short*)(ws);                       // 8 MB (dead after QKV GEMM)
    unsigned short* wqkv  = (unsigned short*)(ws + 8388608);             // 6 MB
    unsigned short* wo    = (unsigned short*)(ws + 14680064);            // 2 MB
    unsigned short* qkv   = (unsigned short*)(ws + 16777216);            // 24 MB
    unsigned short* attn  = (unsigned short*)(ws + 41943040);            // 8 MB
    float*          gaccp = (float*)(ws);                                // 2 MB (overlaps dead xb)
    float*          gms   = (float*)(ws + 2097152);                      // 64 KB

    const int M = B_ * S_;   // 4096

    {
        int total4 = (M * E_ + 4 * E_ * E_) / 4;
        convert_all<<<total4 / 256, 256, 0, stream>>>(x, qw, kw, vw, ow, xb, wqkv, wo);
    }

    // QKV GEMM: [4096][3072] bf16, 256x256 8-phase counted-vmcnt (+rule-#18 fix)
    {
        dim3 grid(M / 256, 3 * E_ / 256);
        gemm_qkv<<<grid, 512, 0, stream>>>(xb, wqkv, qb, kb, vb, qkv, M, 3 * E_, E_);
    }

    // row-streaming global chunks (256) + sparse rows (1024), one dispatch
    attn_fused<<<256 + 1024, 256, 0, stream>>>(qkv, rnd, gaccp, gms, attn);

    // merge global-row partials (128 chunks/tuple, one block per tuple)
    gattn_fin<<<64, 256, 0, stream>>>(gaccp, gms, attn);

    // O GEMM -> fp32 out, 128x128 tile, XCD-swizzled 1D grid
    gemm_o<<<256, 256, 0, stream>>>(attn, wo, ob, out, M, E_, E_);
}

// Round 10
// 167.517 us; speedup vs baseline: 1.0604x; 1.0604x over previous
//
#include <hip/hip_runtime.h>

#define B_  2
#define S_  2048
#define E_  1024
#define H_  16
#define D_  64
#define NGLOB 2
#define NRAND 3
#define WIN 3

typedef __bf16 bf16x8 __attribute__((ext_vector_type(8)));
typedef float  f32x4  __attribute__((ext_vector_type(4)));

__device__ __forceinline__ unsigned short f2bf(float f) {
    unsigned u = __builtin_bit_cast(unsigned, f);
    unsigned r = u + 0x7FFFu + ((u >> 16) & 1u);   // RNE
    return (unsigned short)(r >> 16);
}
__device__ __forceinline__ float bf2f(unsigned short u) {
    return __builtin_bit_cast(float, (unsigned)u << 16);
}

// async global->LDS 16B DMA. LDS dest is wave-uniform base + lane*16.
__device__ __forceinline__ void g2l16(const unsigned short* g, unsigned short* l) {
    __builtin_amdgcn_global_load_lds(
        (const __attribute__((address_space(1))) unsigned*)g,
        (__attribute__((address_space(3))) unsigned*)l, 16, 0, 0);
}

// ---------------- fused fp32 -> bf16 conversion for x + 4 weights ----------------
__global__ __launch_bounds__(256)
void convert_all(const float* __restrict__ x,  const float* __restrict__ qw,
                 const float* __restrict__ kw, const float* __restrict__ vw,
                 const float* __restrict__ ow,
                 unsigned short* __restrict__ xb, unsigned short* __restrict__ wqkv,
                 unsigned short* __restrict__ wo) {
    const int XN = (B_ * S_ * E_) / 4;      // 1048576
    const int WN = (E_ * E_) / 4;           // 262144
    int i = blockIdx.x * blockDim.x + threadIdx.x;
    int r, loc;
    if (i < XN) { r = 0; loc = i; }
    else        { int j = i - XN; r = 1 + (j >> 18); loc = j & (WN - 1); }
    const float* src = r == 0 ? x : r == 1 ? qw : r == 2 ? kw : r == 3 ? vw : ow;
    float4 f = ((const float4*)src)[loc];
    ushort4 u;
    u.x = f2bf(f.x); u.y = f2bf(f.y); u.z = f2bf(f.z); u.w = f2bf(f.w);
    ushort4* dst = r == 0 ? (ushort4*)xb : r == 4 ? (ushort4*)wo
                 : (ushort4*)wqkv + (size_t)(r - 1) * WN;
    dst[loc] = u;
}

// ---------------- QKV GEMM: BK=64, XOR-swizzled LDS (R4 known-good) ---------------
// (256,3): 768-block grid fully resident in ONE round (256 CU x 3) — no tail.
// 8-phase 256^2 schedule dropped permanently: two strikes (R1 176.7, R8 177.6)
// vs this structure's 167-170 — 1 block/CU + K=1024 can't amortize its barriers.
__global__ __launch_bounds__(256, 3)
void gemm_qkv(const unsigned short* __restrict__ A,  // [M][K] bf16
              const unsigned short* __restrict__ W,  // [N][K] bf16
              const float* __restrict__ b0, const float* __restrict__ b1,
              const float* __restrict__ b2,
              unsigned short* __restrict__ Cb, int M, int N, int K) {
    __shared__ unsigned short sA[128 * 64];   // 16 KB
    __shared__ unsigned short sB[128 * 64];   // 16 KB
    const int t = threadIdx.x;
    const int lane = t & 63;
    const int wave = t >> 6;
    const int wm = wave >> 1, wn = wave & 1;
    const int lq = lane >> 4;
    const int lr = lane & 15;
    const int bm = blockIdx.x * 128;
    const int bn = blockIdx.y * 128;

    f32x4 acc[4][4] = {};

    for (int k0 = 0; k0 < K; k0 += 64) {
        const unsigned short* Abase = A + (size_t)bm * K + k0;
        const unsigned short* Wbase = W + (size_t)bn * K + k0;
        #pragma unroll
        for (int j = 0; j < 4; ++j) {             // 1024 chunks each
            int c = j * 256 + t;
            int row = c >> 3, cc = c & 7;
            int gcol = ((cc ^ (row & 7)) << 3);   // swizzled source col
            int dst = j * 2048 + wave * 512;      // wave-uniform elem offset
            g2l16(Abase + (size_t)row * K + gcol, sA + dst);
            g2l16(Wbase + (size_t)row * K + gcol, sB + dst);
        }
        __syncthreads();

        #pragma unroll
        for (int ks = 0; ks < 2; ++ks) {
            const int sw = (((ks << 2) + lq) ^ (lr & 7)) << 3;
            bf16x8 af[4], bfr[4];
            #pragma unroll
            for (int i = 0; i < 4; ++i)
                af[i] = *(const bf16x8*)&sA[(wm * 64 + i * 16 + lr) * 64 + sw];
            #pragma unroll
            for (int j = 0; j < 4; ++j)
                bfr[j] = *(const bf16x8*)&sB[(wn * 64 + j * 16 + lr) * 64 + sw];
            #pragma unroll
            for (int i = 0; i < 4; ++i)
                #pragma unroll
                for (int j = 0; j < 4; ++j)
                    acc[i][j] = __builtin_amdgcn_mfma_f32_16x16x32_bf16(af[i], bfr[j], acc[i][j], 0, 0, 0);
        }
        __syncthreads();
    }

    #pragma unroll
    for (int i = 0; i < 4; ++i) {
        int row0 = bm + wm * 64 + i * 16 + lq * 4;
        #pragma unroll
        for (int j = 0; j < 4; ++j) {
            int col = bn + wn * 64 + j * 16 + lr;
            const float* bp = col < E_ ? b0 : (col < 2 * E_ ? b1 : b2);
            float bv = bp[col & (E_ - 1)];
            #pragma unroll
            for (int r = 0; r < 4; ++r)
                Cb[(size_t)(row0 + r) * N + col] = f2bf(acc[i][j][r] + bv);
        }
    }
}

// ---------------- O GEMM: 128x64 tile, BK=64 XOR-swizzled, fused global-row merge -
// R9: blocks with bm==0 / bm==2048 (the only consumers of attn rows {0,1} per
// batch) first compute the 8-chunk flash merge for their 2 global rows, write the
// bf16 values to the attn buffer, vmcnt(0)+barrier, then stage normally (self-read
// through own L2). 16 blocks per batch redundantly write IDENTICAL bytes — benign.
// Removes the gattn_fin dispatch entirely (5 -> 4 dispatches).
__global__ __launch_bounds__(256, 2)
void gemm_o64(unsigned short* A,                      // attn (read + global-row write)
              const unsigned short* __restrict__ W,   // [N][K] bf16 (wo)
              const float* __restrict__ bias,
              const float* __restrict__ gaccp, const float* __restrict__ gms,
              float* __restrict__ Cf, int M, int N, int K) {
    __shared__ unsigned short sA[128 * 64];   // 16 KB
    __shared__ unsigned short sB[64 * 64];    // 8 KB
    const int t = threadIdx.x;
    const int lane = t & 63;
    const int wave = t >> 6;
    const int lq = lane >> 4;
    const int lr = lane & 15;
    const int bm = blockIdx.x * 128;
    const int bn = blockIdx.y * 64;

    // ---- fused gattn_fin for this tile's global rows ----
    if (blockIdx.x == 0 || blockIdx.x == 16) {
        int b = blockIdx.x >> 4;
        #pragma unroll
        for (int r = 0; r < 8; ++r) {
            int oid = r * 256 + t;              // 0..2047 : i2*1024 + col
            int i2 = oid >> 10, col = oid & 1023;
            int h = col >> 6, d = col & 63;
            int tup = b * 32 + i2 * 16 + h;
            float Mx = -1e30f;
            #pragma unroll
            for (int c = 0; c < 8; ++c) Mx = fmaxf(Mx, gms[(tup * 8 + c) * 2]);
            float den = 0.f, num = 0.f;
            #pragma unroll
            for (int c = 0; c < 8; ++c) {
                float f = __expf(gms[(tup * 8 + c) * 2] - Mx);
                den += gms[(tup * 8 + c) * 2 + 1] * f;
                num += gaccp[(size_t)(tup * 8 + c) * D_ + d] * f;
            }
            A[(size_t)(b * S_ + i2) * E_ + col] = f2bf(num / den);
        }
        asm volatile("s_waitcnt vmcnt(0)" ::: "memory");
    }
    __syncthreads();

    f32x4 acc[2][4] = {};

    for (int k0 = 0; k0 < K; k0 += 64) {
        const unsigned short* Abase = A + (size_t)bm * K + k0;
        const unsigned short* Wbase = W + (size_t)bn * K + k0;
        #pragma unroll
        for (int j = 0; j < 4; ++j) {           // A: 1024 chunks
            int c = j * 256 + t;
            int row = c >> 3, cc = c & 7;
            int gcol = ((cc ^ (row & 7)) << 3);
            int dst = j * 2048 + wave * 512;
            g2l16(Abase + (size_t)row * K + gcol, sA + dst);
        }
        #pragma unroll
        for (int j = 0; j < 2; ++j) {           // B: 512 chunks
            int c = j * 256 + t;
            int row = c >> 3, cc = c & 7;
            int gcol = ((cc ^ (row & 7)) << 3);
            int dst = j * 2048 + wave * 512;
            g2l16(Wbase + (size_t)row * K + gcol, sB + dst);
        }
        __syncthreads();

        #pragma unroll
        for (int ks = 0; ks < 2; ++ks) {
            const int sw = (((ks << 2) + lq) ^ (lr & 7)) << 3;
            bf16x8 af[2], bfr[4];
            #pragma unroll
            for (int i = 0; i < 2; ++i)
                af[i] = *(const bf16x8*)&sA[(wave * 32 + i * 16 + lr) * 64 + sw];
            #pragma unroll
            for (int j = 0; j < 4; ++j)
                bfr[j] = *(const bf16x8*)&sB[(j * 16 + lr) * 64 + sw];
            #pragma unroll
            for (int i = 0; i < 2; ++i)
                #pragma unroll
                for (int j = 0; j < 4; ++j)
                    acc[i][j] = __builtin_amdgcn_mfma_f32_16x16x32_bf16(af[i], bfr[j], acc[i][j], 0, 0, 0);
        }
        __syncthreads();
    }

    #pragma unroll
    for (int i = 0; i < 2; ++i) {
        int row0 = bm + wave * 32 + i * 16 + lq * 4;
        #pragma unroll
        for (int j = 0; j < 4; ++j) {
            int col = bn + j * 16 + lr;
            float bv = bias[col];
            #pragma unroll
            for (int r = 0; r < 4; ++r)
                Cf[(size_t)(row0 + r) * N + col] = acc[i][j][r] + bv;
        }
    }
}

// ---------------- fused: flash-style global chunks + sparse rows -----------------
// blocks [0,512) = (tuple x 256-key chunk), coalesced flash-partial (R4, best
// measured). blocks [512,1536) = sparse rows, one wave per row.
__global__ __launch_bounds__(256)
void attn_fused(const unsigned short* __restrict__ qkv,
                const int* __restrict__ rnd,
                float* __restrict__ gaccp, float* __restrict__ gms,
                unsigned short* __restrict__ attn) {
    const int NB = B_ * (S_ - 2);     // 4092
    int t = threadIdx.x;

    if (blockIdx.x < 512) {
        // ---- one (tuple, key-chunk) per block ----
        int tup = blockIdx.x >> 3, seg = blockIdx.x & 7;
        int b = tup >> 5, i = (tup >> 4) & 1, h = tup & 15;
        int w = t >> 6, l = t & 63;
        __shared__ float ps[256];
        __shared__ float red[4];
        __shared__ float ov[4][D_];

        // q chunk for this lane: 8 bf16 at chunk (l&7) of head slice
        const bf16x8* qp = (const bf16x8*)(qkv + (size_t)(b * S_ + i) * 3072 + h * D_);
        bf16x8 qv = qp[l & 7];
        float qreg[8];
        #pragma unroll
        for (int j = 0; j < 8; ++j) qreg[j] = (float)qv[j];

        // scores: wave w covers keys [seg*256 + w*64, +64), 8 keys/iter
        const int key0 = seg * 256 + w * 64;
        float sc[8];
        #pragma unroll
        for (int it = 0; it < 8; ++it) {
            int key = key0 + it * 8 + (l >> 3);
            const bf16x8* kp = (const bf16x8*)(qkv + (size_t)(b * S_ + key) * 3072 + E_ + h * D_);
            bf16x8 kv = kp[l & 7];
            float s = 0.f;
            #pragma unroll
            for (int j = 0; j < 8; ++j) s += qreg[j] * (float)kv[j];
            s += __shfl_xor(s, 1);
            s += __shfl_xor(s, 2);
            s += __shfl_xor(s, 4);
            sc[it] = s * 0.125f;
        }
        #pragma unroll
        for (int it = 0; it < 8; ++it)
            if ((l & 7) == 0) ps[w * 64 + it * 8 + (l >> 3)] = sc[it];
        __syncthreads();

        // chunk-local softmax partials
        float v = ps[t];
        float m = v;
        #pragma unroll
        for (int o = 32; o; o >>= 1) m = fmaxf(m, __shfl_xor(m, o));
        if (l == 0) red[w] = m;
        __syncthreads();
        m = fmaxf(fmaxf(red[0], red[1]), fmaxf(red[2], red[3]));
        float e = __expf(v - m);
        float sum = e;
        #pragma unroll
        for (int o = 32; o; o >>= 1) sum += __shfl_xor(sum, o);
        __syncthreads();
        if (l == 0) red[w] = sum;
        ps[t] = e;                       // unnormalized probs
        __syncthreads();
        if (t == 0) {
            float stot = red[0] + red[1] + red[2] + red[3];
            gms[(tup * 8 + seg) * 2]     = m;
            gms[(tup * 8 + seg) * 2 + 1] = stot;
        }

        // PV over this chunk: wave w keys [key0, +64), lane l = dim
        const unsigned short* vbase =
            qkv + (size_t)(b * S_ + key0) * 3072 + 2 * E_ + h * D_ + l;
        const float* pw = ps + w * 64;
        float acc = 0.f;
        #pragma unroll 8
        for (int k = 0; k < 64; ++k)
            acc += pw[k] * bf2f(vbase[(size_t)k * 3072]);
        ov[w][l] = acc;
        __syncthreads();
        if (w == 0)
            gaccp[((size_t)tup * 8 + seg) * D_ + l] =
                ov[0][l] + ov[1][l] + ov[2][l] + ov[3][l];
        return;
    }

    // ---- sparse rows: one wave per row ----
    int bb = blockIdx.x - 512;                        // [0,1024)
    int bidx = (bb & 7) * 128 + (bb >> 3);            // XCD swizzle
    int w = t >> 6, l = t & 63;
    int row = bidx * 4 + w;
    bool valid = row < NB;
    int b = row / (S_ - 2);
    int i = row % (S_ - 2) + 2;
    if (!valid) { b = 0; i = 2; }

    __shared__ int   cols_s[4][12];
    __shared__ int   ncol_sh[4];
    __shared__ float pr_s[4][16 * 13 + 3];

    const bf16x8* qp = (const bf16x8*)(qkv + (size_t)(b * S_ + i) * 3072);
    bf16x8 q0 = qp[l * 2], q1 = qp[l * 2 + 1];
    float qreg[16];
    #pragma unroll
    for (int j = 0; j < 8; ++j) { qreg[j] = (float)q0[j]; qreg[8 + j] = (float)q1[j]; }

    if (l == 0) {
        int* cols = cols_s[w];
        int n = 0;
        cols[n++] = 0; cols[n++] = 1;
        int lo = i - WIN; if (lo < NGLOB) lo = NGLOB;
        int hi = i + WIN; if (hi > S_ - 1) hi = S_ - 1;
        for (int j = lo; j <= hi; ++j) cols[n++] = j;
        for (int r = 0; r < NRAND; ++r) {
            int c = rnd[i * NRAND + r];
            bool dup = false;
            for (int q = 0; q < n; ++q) dup = dup || (cols[q] == c);
            if (!dup) cols[n++] = c;
        }
        ncol_sh[w] = n;
        for (int q = n; q < 12; ++q) cols[q] = 0;
    }
    __syncthreads();
    const int n = ncol_sh[w];
    const int h4 = l >> 2;

    float sco[12];
    #pragma unroll
    for (int c = 0; c < 12; ++c) {
        const bf16x8* kp = (const bf16x8*)(qkv + (size_t)(b * S_ + cols_s[w][c]) * 3072 + E_);
        bf16x8 k0 = kp[l * 2], k1 = kp[l * 2 + 1];
        float s = 0.f;
        #pragma unroll
        for (int j = 0; j < 8; ++j) s += qreg[j] * (float)k0[j] + qreg[8 + j] * (float)k1[j];
        s += __shfl_xor(s, 1);
        s += __shfl_xor(s, 2);
        sco[c] = (c < n) ? s * 0.125f : -1e30f;
    }

    if ((l & 3) == 0) {
        float m = -1e30f;
        #pragma unroll
        for (int c = 0; c < 12; ++c) m = fmaxf(m, sco[c]);
        float sum = 0.f;
        #pragma unroll
        for (int c = 0; c < 12; ++c) { float e = __expf(sco[c] - m); sco[c] = e; sum += e; }
        float inv = 1.f / sum;
        #pragma unroll
        for (int c = 0; c < 12; ++c) pr_s[w][h4 * 13 + c] = sco[c] * inv;
    }
    __syncthreads();

    float o[16] = {};
    #pragma unroll
    for (int c = 0; c < 12; ++c) {
        float p = pr_s[w][h4 * 13 + c];
        const bf16x8* vp = (const bf16x8*)(qkv + (size_t)(b * S_ + cols_s[w][c]) * 3072 + 2 * E_);
        bf16x8 v0 = vp[l * 2], v1 = vp[l * 2 + 1];
        #pragma unroll
        for (int j = 0; j < 8; ++j) { o[j] += p * (float)v0[j]; o[8 + j] += p * (float)v1[j]; }
    }

    if (valid) {
        ushort4 u0, u1, u2, u3;
        u0.x = f2bf(o[0]);  u0.y = f2bf(o[1]);  u0.z = f2bf(o[2]);  u0.w = f2bf(o[3]);
        u1.x = f2bf(o[4]);  u1.y = f2bf(o[5]);  u1.z = f2bf(o[6]);  u1.w = f2bf(o[7]);
        u2.x = f2bf(o[8]);  u2.y = f2bf(o[9]);  u2.z = f2bf(o[10]); u2.w = f2bf(o[11]);
        u3.x = f2bf(o[12]); u3.y = f2bf(o[13]); u3.z = f2bf(o[14]); u3.w = f2bf(o[15]);
        ushort4* op = (ushort4*)(attn + (size_t)(b * S_ + i) * E_ + l * 16);
        op[0] = u0; op[1] = u1; op[2] = u2; op[3] = u3;
    }
}

extern "C" void kernel_launch(void* const* d_in, const int* in_sizes, int n_in,
                              void* d_out, int out_size, void* d_ws, size_t ws_size,
                              hipStream_t stream) {
    const float* x   = (const float*)d_in[0];
    const int*   rnd = (const int*)d_in[1];
    const float* qw  = (const float*)d_in[2];
    const float* qb  = (const float*)d_in[3];
    const float* kw  = (const float*)d_in[4];
    const float* kb  = (const float*)d_in[5];
    const float* vw  = (const float*)d_in[6];
    const float* vb  = (const float*)d_in[7];
    const float* ow  = (const float*)d_in[8];
    const float* ob  = (const float*)d_in[9];
    float* out = (float*)d_out;

    char* ws = (char*)d_ws;
    unsigned short* xb    = (unsigned short*)(ws);                       // 8 MB (dead after QKV GEMM)
    unsigned short* wqkv  = (unsigned short*)(ws + 8388608);             // 6 MB
    unsigned short* wo    = (unsigned short*)(ws + 14680064);            // 2 MB
    unsigned short* qkv   = (unsigned short*)(ws + 16777216);            // 24 MB
    unsigned short* attn  = (unsigned short*)(ws + 41943040);            // 8 MB
    float*          gaccp = (float*)(ws);                                // 128 KB (overlaps dead xb)
    float*          gms   = (float*)(ws + 131072);                       // 4 KB

    const int M = B_ * S_;   // 4096

    {
        int total4 = (M * E_ + 4 * E_ * E_) / 4;
        convert_all<<<total4 / 256, 256, 0, stream>>>(x, qw, kw, vw, ow, xb, wqkv, wo);
    }

    // QKV GEMM: [4096][3072] bf16, BK=64 swizzled, fully-resident grid
    {
        dim3 grid(M / 128, 3 * E_ / 128);
        gemm_qkv<<<grid, 256, 0, stream>>>(xb, wqkv, qb, kb, vb, qkv, M, 3 * E_, E_);
    }

    // global chunks (512, flash-partial) + sparse rows (1024), one dispatch
    attn_fused<<<512 + 1024, 256, 0, stream>>>(qkv, rnd, gaccp, gms, attn);

    // O GEMM -> fp32 out (BK=64 swizzled) with fused global-row merge (no fin dispatch)
    {
        dim3 grid(M / 128, E_ / 64);
        gemm_o64<<<grid, 256, 0, stream>>>(attn, wo, ob, gaccp, gms, out, M, E_, E_);
    }
}

// Round 11
// 165.788 us; speedup vs baseline: 1.0715x; 1.0104x over previous
//
#include <hip/hip_runtime.h>

#define B_  2
#define S_  2048
#define E_  1024
#define H_  16
#define D_  64
#define NGLOB 2
#define NRAND 3
#define WIN 3

typedef __bf16 bf16x8 __attribute__((ext_vector_type(8)));
typedef float  f32x4  __attribute__((ext_vector_type(4)));

__device__ __forceinline__ unsigned short f2bf(float f) {
    unsigned u = __builtin_bit_cast(unsigned, f);
    unsigned r = u + 0x7FFFu + ((u >> 16) & 1u);   // RNE
    return (unsigned short)(r >> 16);
}
__device__ __forceinline__ float bf2f(unsigned short u) {
    return __builtin_bit_cast(float, (unsigned)u << 16);
}

// async global->LDS 16B DMA. LDS dest is wave-uniform base + lane*16.
__device__ __forceinline__ void g2l16(const unsigned short* g, unsigned short* l) {
    __builtin_amdgcn_global_load_lds(
        (const __attribute__((address_space(1))) unsigned*)g,
        (__attribute__((address_space(3))) unsigned*)l, 16, 0, 0);
}

// ---------------- fused fp32 -> bf16 conversion for x + 4 weights ----------------
__global__ __launch_bounds__(256)
void convert_all(const float* __restrict__ x,  const float* __restrict__ qw,
                 const float* __restrict__ kw, const float* __restrict__ vw,
                 const float* __restrict__ ow,
                 unsigned short* __restrict__ xb, unsigned short* __restrict__ wqkv,
                 unsigned short* __restrict__ wo) {
    const int XN = (B_ * S_ * E_) / 4;      // 1048576
    const int WN = (E_ * E_) / 4;           // 262144
    int i = blockIdx.x * blockDim.x + threadIdx.x;
    int r, loc;
    if (i < XN) { r = 0; loc = i; }
    else        { int j = i - XN; r = 1 + (j >> 18); loc = j & (WN - 1); }
    const float* src = r == 0 ? x : r == 1 ? qw : r == 2 ? kw : r == 3 ? vw : ow;
    float4 f = ((const float4*)src)[loc];
    ushort4 u;
    u.x = f2bf(f.x); u.y = f2bf(f.y); u.z = f2bf(f.z); u.w = f2bf(f.w);
    ushort4* dst = r == 0 ? (ushort4*)xb : r == 4 ? (ushort4*)wo
                 : (ushort4*)wqkv + (size_t)(r - 1) * WN;
    dst[loc] = u;
}

// ---------------- QKV GEMM: BK=64, XOR-swizzled LDS (known-good) ------------------
__global__ __launch_bounds__(256, 3)
void gemm_qkv(const unsigned short* __restrict__ A,  // [M][K] bf16
              const unsigned short* __restrict__ W,  // [N][K] bf16
              const float* __restrict__ b0, const float* __restrict__ b1,
              const float* __restrict__ b2,
              unsigned short* __restrict__ Cb, int M, int N, int K) {
    __shared__ unsigned short sA[128 * 64];   // 16 KB
    __shared__ unsigned short sB[128 * 64];   // 16 KB
    const int t = threadIdx.x;
    const int lane = t & 63;
    const int wave = t >> 6;
    const int wm = wave >> 1, wn = wave & 1;
    const int lq = lane >> 4;
    const int lr = lane & 15;
    const int bm = blockIdx.x * 128;
    const int bn = blockIdx.y * 128;

    f32x4 acc[4][4] = {};

    for (int k0 = 0; k0 < K; k0 += 64) {
        const unsigned short* Abase = A + (size_t)bm * K + k0;
        const unsigned short* Wbase = W + (size_t)bn * K + k0;
        #pragma unroll
        for (int j = 0; j < 4; ++j) {             // 1024 chunks each
            int c = j * 256 + t;
            int row = c >> 3, cc = c & 7;
            int gcol = ((cc ^ (row & 7)) << 3);   // swizzled source col
            int dst = j * 2048 + wave * 512;      // wave-uniform elem offset
            g2l16(Abase + (size_t)row * K + gcol, sA + dst);
            g2l16(Wbase + (size_t)row * K + gcol, sB + dst);
        }
        __syncthreads();

        #pragma unroll
        for (int ks = 0; ks < 2; ++ks) {
            const int sw = (((ks << 2) + lq) ^ (lr & 7)) << 3;
            bf16x8 af[4], bfr[4];
            #pragma unroll
            for (int i = 0; i < 4; ++i)
                af[i] = *(const bf16x8*)&sA[(wm * 64 + i * 16 + lr) * 64 + sw];
            #pragma unroll
            for (int j = 0; j < 4; ++j)
                bfr[j] = *(const bf16x8*)&sB[(wn * 64 + j * 16 + lr) * 64 + sw];
            #pragma unroll
            for (int i = 0; i < 4; ++i)
                #pragma unroll
                for (int j = 0; j < 4; ++j)
                    acc[i][j] = __builtin_amdgcn_mfma_f32_16x16x32_bf16(af[i], bfr[j], acc[i][j], 0, 0, 0);
        }
        __syncthreads();
    }

    #pragma unroll
    for (int i = 0; i < 4; ++i) {
        int row0 = bm + wm * 64 + i * 16 + lq * 4;
        #pragma unroll
        for (int j = 0; j < 4; ++j) {
            int col = bn + wn * 64 + j * 16 + lr;
            const float* bp = col < E_ ? b0 : (col < 2 * E_ ? b1 : b2);
            float bv = bp[col & (E_ - 1)];
            #pragma unroll
            for (int r = 0; r < 4; ++r)
                Cb[(size_t)(row0 + r) * N + col] = f2bf(acc[i][j][r] + bv);
        }
    }
}

// ---------------- O GEMM: 128x128 tile (R11), fused global-row merge --------------
// R11: 256 blocks (32x8), 3/CU fully resident, 2x MFMA:staging ratio of 128x64.
// Blocks with bm==0 / bm==2048 (sole consumers of attn rows {0,1} per batch)
// first compute the 8-chunk flash merge for their 2 global rows, write bf16 to
// attn, vmcnt(0)+barrier, then stage normally (self-read through own L2).
// 8 blocks per batch redundantly write IDENTICAL bytes — benign.
__global__ __launch_bounds__(256, 3)
void gemm_o(unsigned short* A,                      // attn (read + global-row write)
            const unsigned short* __restrict__ W,   // [N][K] bf16 (wo)
            const float* __restrict__ bias,
            const float* __restrict__ gaccp, const float* __restrict__ gms,
            float* __restrict__ Cf, int M, int N, int K) {
    __shared__ unsigned short sA[128 * 64];   // 16 KB
    __shared__ unsigned short sB[128 * 64];   // 16 KB
    const int t = threadIdx.x;
    const int lane = t & 63;
    const int wave = t >> 6;
    const int wm = wave >> 1, wn = wave & 1;
    const int lq = lane >> 4;
    const int lr = lane & 15;
    const int bm = blockIdx.x * 128;
    const int bn = blockIdx.y * 128;

    // ---- fused gattn_fin for this tile's global rows ----
    if (blockIdx.x == 0 || blockIdx.x == 16) {
        int b = blockIdx.x >> 4;
        #pragma unroll
        for (int r = 0; r < 8; ++r) {
            int oid = r * 256 + t;              // 0..2047 : i2*1024 + col
            int i2 = oid >> 10, col = oid & 1023;
            int h = col >> 6, d = col & 63;
            int tup = b * 32 + i2 * 16 + h;
            float Mx = -1e30f;
            #pragma unroll
            for (int c = 0; c < 8; ++c) Mx = fmaxf(Mx, gms[(tup * 8 + c) * 2]);
            float den = 0.f, num = 0.f;
            #pragma unroll
            for (int c = 0; c < 8; ++c) {
                float f = __expf(gms[(tup * 8 + c) * 2] - Mx);
                den += gms[(tup * 8 + c) * 2 + 1] * f;
                num += gaccp[(size_t)(tup * 8 + c) * D_ + d] * f;
            }
            A[(size_t)(b * S_ + i2) * E_ + col] = f2bf(num / den);
        }
        asm volatile("s_waitcnt vmcnt(0)" ::: "memory");
    }
    __syncthreads();

    f32x4 acc[4][4] = {};

    for (int k0 = 0; k0 < K; k0 += 64) {
        const unsigned short* Abase = A + (size_t)bm * K + k0;
        const unsigned short* Wbase = W + (size_t)bn * K + k0;
        #pragma unroll
        for (int j = 0; j < 4; ++j) {
            int c = j * 256 + t;
            int row = c >> 3, cc = c & 7;
            int gcol = ((cc ^ (row & 7)) << 3);
            int dst = j * 2048 + wave * 512;
            g2l16(Abase + (size_t)row * K + gcol, sA + dst);
            g2l16(Wbase + (size_t)row * K + gcol, sB + dst);
        }
        __syncthreads();

        #pragma unroll
        for (int ks = 0; ks < 2; ++ks) {
            const int sw = (((ks << 2) + lq) ^ (lr & 7)) << 3;
            bf16x8 af[4], bfr[4];
            #pragma unroll
            for (int i = 0; i < 4; ++i)
                af[i] = *(const bf16x8*)&sA[(wm * 64 + i * 16 + lr) * 64 + sw];
            #pragma unroll
            for (int j = 0; j < 4; ++j)
                bfr[j] = *(const bf16x8*)&sB[(wn * 64 + j * 16 + lr) * 64 + sw];
            #pragma unroll
            for (int i = 0; i < 4; ++i)
                #pragma unroll
                for (int j = 0; j < 4; ++j)
                    acc[i][j] = __builtin_amdgcn_mfma_f32_16x16x32_bf16(af[i], bfr[j], acc[i][j], 0, 0, 0);
        }
        __syncthreads();
    }

    #pragma unroll
    for (int i = 0; i < 4; ++i) {
        int row0 = bm + wm * 64 + i * 16 + lq * 4;
        #pragma unroll
        for (int j = 0; j < 4; ++j) {
            int col = bn + wn * 64 + j * 16 + lr;
            float bv = bias[col];
            #pragma unroll
            for (int r = 0; r < 4; ++r)
                Cf[(size_t)(row0 + r) * N + col] = acc[i][j][r] + bv;
        }
    }
}

// ---------------- fused: flash-style global chunks + sparse rows -----------------
// blocks [0,512) = (tuple x 256-key chunk) flash-partial. R11: PV loads
// vectorized — lane=(key-sub l>>3, dim-group l&7); each instr reads 8 V rows x
// 128B fully packed (was 64 rows x 2B, 1.6% line use); 8 iters instead of 64;
// 3-level shfl_xor (8/16/32) reduces over key-subs. blocks [512,1536) = sparse.
__global__ __launch_bounds__(256)
void attn_fused(const unsigned short* __restrict__ qkv,
                const int* __restrict__ rnd,
                float* __restrict__ gaccp, float* __restrict__ gms,
                unsigned short* __restrict__ attn) {
    const int NB = B_ * (S_ - 2);     // 4092
    int t = threadIdx.x;

    if (blockIdx.x < 512) {
        // ---- one (tuple, key-chunk) per block ----
        int tup = blockIdx.x >> 3, seg = blockIdx.x & 7;
        int b = tup >> 5, i = (tup >> 4) & 1, h = tup & 15;
        int w = t >> 6, l = t & 63;
        __shared__ float ps[256];
        __shared__ float red[4];
        __shared__ float ov[4][D_];

        // q chunk for this lane: 8 bf16 at chunk (l&7) of head slice
        const bf16x8* qp = (const bf16x8*)(qkv + (size_t)(b * S_ + i) * 3072 + h * D_);
        bf16x8 qv = qp[l & 7];
        float qreg[8];
        #pragma unroll
        for (int j = 0; j < 8; ++j) qreg[j] = (float)qv[j];

        // scores: wave w covers keys [seg*256 + w*64, +64), 8 keys/iter
        const int key0 = seg * 256 + w * 64;
        float sc[8];
        #pragma unroll
        for (int it = 0; it < 8; ++it) {
            int key = key0 + it * 8 + (l >> 3);
            const bf16x8* kp = (const bf16x8*)(qkv + (size_t)(b * S_ + key) * 3072 + E_ + h * D_);
            bf16x8 kv = kp[l & 7];
            float s = 0.f;
            #pragma unroll
            for (int j = 0; j < 8; ++j) s += qreg[j] * (float)kv[j];
            s += __shfl_xor(s, 1);
            s += __shfl_xor(s, 2);
            s += __shfl_xor(s, 4);
            sc[it] = s * 0.125f;
        }
        #pragma unroll
        for (int it = 0; it < 8; ++it)
            if ((l & 7) == 0) ps[w * 64 + it * 8 + (l >> 3)] = sc[it];
        __syncthreads();

        // chunk-local softmax partials
        float v = ps[t];
        float m = v;
        #pragma unroll
        for (int o = 32; o; o >>= 1) m = fmaxf(m, __shfl_xor(m, o));
        if (l == 0) red[w] = m;
        __syncthreads();
        m = fmaxf(fmaxf(red[0], red[1]), fmaxf(red[2], red[3]));
        float e = __expf(v - m);
        float sum = e;
        #pragma unroll
        for (int o = 32; o; o >>= 1) sum += __shfl_xor(sum, o);
        __syncthreads();
        if (l == 0) red[w] = sum;
        ps[t] = e;                       // unnormalized probs
        __syncthreads();
        if (t == 0) {
            float stot = red[0] + red[1] + red[2] + red[3];
            gms[(tup * 8 + seg) * 2]     = m;
            gms[(tup * 8 + seg) * 2 + 1] = stot;
        }

        // PV over this chunk, vectorized: wave w keys [key0,+64);
        // lane = (ksb = l>>3 key-sub, dg = l&7 dim-group of 8 dims)
        const int ksb = l >> 3, dg = l & 7;
        float o[8] = {};
        #pragma unroll
        for (int kk = 0; kk < 8; ++kk) {
            int key = key0 + kk * 8 + ksb;
            const bf16x8* vp = (const bf16x8*)(qkv + (size_t)(b * S_ + key) * 3072
                                               + 2 * E_ + h * D_ + dg * 8);
            bf16x8 vv = *vp;
            float p = ps[w * 64 + kk * 8 + ksb];
            #pragma unroll
            for (int e2 = 0; e2 < 8; ++e2) o[e2] += p * (float)vv[e2];
        }
        #pragma unroll
        for (int mask = 8; mask <= 32; mask <<= 1)
            #pragma unroll
            for (int e2 = 0; e2 < 8; ++e2) o[e2] += __shfl_xor(o[e2], mask);
        if (ksb == 0)
            #pragma unroll
            for (int e2 = 0; e2 < 8; ++e2) ov[w][dg * 8 + e2] = o[e2];
        __syncthreads();
        if (w == 0)
            gaccp[((size_t)tup * 8 + seg) * D_ + l] =
                ov[0][l] + ov[1][l] + ov[2][l] + ov[3][l];
        return;
    }

    // ---- sparse rows: one wave per row ----
    int bb = blockIdx.x - 512;                        // [0,1024)
    int bidx = (bb & 7) * 128 + (bb >> 3);            // XCD swizzle
    int w = t >> 6, l = t & 63;
    int row = bidx * 4 + w;
    bool valid = row < NB;
    int b = row / (S_ - 2);
    int i = row % (S_ - 2) + 2;
    if (!valid) { b = 0; i = 2; }

    __shared__ int   cols_s[4][12];
    __shared__ int   ncol_sh[4];
    __shared__ float pr_s[4][16 * 13 + 3];

    const bf16x8* qp = (const bf16x8*)(qkv + (size_t)(b * S_ + i) * 3072);
    bf16x8 q0 = qp[l * 2], q1 = qp[l * 2 + 1];
    float qreg[16];
    #pragma unroll
    for (int j = 0; j < 8; ++j) { qreg[j] = (float)q0[j]; qreg[8 + j] = (float)q1[j]; }

    if (l == 0) {
        int* cols = cols_s[w];
        int n = 0;
        cols[n++] = 0; cols[n++] = 1;
        int lo = i - WIN; if (lo < NGLOB) lo = NGLOB;
        int hi = i + WIN; if (hi > S_ - 1) hi = S_ - 1;
        for (int j = lo; j <= hi; ++j) cols[n++] = j;
        for (int r = 0; r < NRAND; ++r) {
            int c = rnd[i * NRAND + r];
            bool dup = false;
            for (int q = 0; q < n; ++q) dup = dup || (cols[q] == c);
            if (!dup) cols[n++] = c;
        }
        ncol_sh[w] = n;
        for (int q = n; q < 12; ++q) cols[q] = 0;
    }
    __syncthreads();
    const int n = ncol_sh[w];
    const int h4 = l >> 2;

    float sco[12];
    #pragma unroll
    for (int c = 0; c < 12; ++c) {
        const bf16x8* kp = (const bf16x8*)(qkv + (size_t)(b * S_ + cols_s[w][c]) * 3072 + E_);
        bf16x8 k0 = kp[l * 2], k1 = kp[l * 2 + 1];
        float s = 0.f;
        #pragma unroll
        for (int j = 0; j < 8; ++j) s += qreg[j] * (float)k0[j] + qreg[8 + j] * (float)k1[j];
        s += __shfl_xor(s, 1);
        s += __shfl_xor(s, 2);
        sco[c] = (c < n) ? s * 0.125f : -1e30f;
    }

    if ((l & 3) == 0) {
        float m = -1e30f;
        #pragma unroll
        for (int c = 0; c < 12; ++c) m = fmaxf(m, sco[c]);
        float sum = 0.f;
        #pragma unroll
        for (int c = 0; c < 12; ++c) { float e = __expf(sco[c] - m); sco[c] = e; sum += e; }
        float inv = 1.f / sum;
        #pragma unroll
        for (int c = 0; c < 12; ++c) pr_s[w][h4 * 13 + c] = sco[c] * inv;
    }
    __syncthreads();

    float o[16] = {};
    #pragma unroll
    for (int c = 0; c < 12; ++c) {
        float p = pr_s[w][h4 * 13 + c];
        const bf16x8* vp = (const bf16x8*)(qkv + (size_t)(b * S_ + cols_s[w][c]) * 3072 + 2 * E_);
        bf16x8 v0 = vp[l * 2], v1 = vp[l * 2 + 1];
        #pragma unroll
        for (int j = 0; j < 8; ++j) { o[j] += p * (float)v0[j]; o[8 + j] += p * (float)v1[j]; }
    }

    if (valid) {
        ushort4 u0, u1, u2, u3;
        u0.x = f2bf(o[0]);  u0.y = f2bf(o[1]);  u0.z = f2bf(o[2]);  u0.w = f2bf(o[3]);
        u1.x = f2bf(o[4]);  u1.y = f2bf(o[5]);  u1.z = f2bf(o[6]);  u1.w = f2bf(o[7]);
        u2.x = f2bf(o[8]);  u2.y = f2bf(o[9]);  u2.z = f2bf(o[10]); u2.w = f2bf(o[11]);
        u3.x = f2bf(o[12]); u3.y = f2bf(o[13]); u3.z = f2bf(o[14]); u3.w = f2bf(o[15]);
        ushort4* op = (ushort4*)(attn + (size_t)(b * S_ + i) * E_ + l * 16);
        op[0] = u0; op[1] = u1; op[2] = u2; op[3] = u3;
    }
}

extern "C" void kernel_launch(void* const* d_in, const int* in_sizes, int n_in,
                              void* d_out, int out_size, void* d_ws, size_t ws_size,
                              hipStream_t stream) {
    const float* x   = (const float*)d_in[0];
    const int*   rnd = (const int*)d_in[1];
    const float* qw  = (const float*)d_in[2];
    const float* qb  = (const float*)d_in[3];
    const float* kw  = (const float*)d_in[4];
    const float* kb  = (const float*)d_in[5];
    const float* vw  = (const float*)d_in[6];
    const float* vb  = (const float*)d_in[7];
    const float* ow  = (const float*)d_in[8];
    const float* ob  = (const float*)d_in[9];
    float* out = (float*)d_out;

    char* ws = (char*)d_ws;
    unsigned short* xb    = (unsigned short*)(ws);                       // 8 MB (dead after QKV GEMM)
    unsigned short* wqkv  = (unsigned short*)(ws + 8388608);             // 6 MB
    unsigned short* wo    = (unsigned short*)(ws + 14680064);            // 2 MB
    unsigned short* qkv   = (unsigned short*)(ws + 16777216);            // 24 MB
    unsigned short* attn  = (unsigned short*)(ws + 41943040);            // 8 MB
    float*          gaccp = (float*)(ws);                                // 128 KB (overlaps dead xb)
    float*          gms   = (float*)(ws + 131072);                       // 4 KB

    const int M = B_ * S_;   // 4096

    {
        int total4 = (M * E_ + 4 * E_ * E_) / 4;
        convert_all<<<total4 / 256, 256, 0, stream>>>(x, qw, kw, vw, ow, xb, wqkv, wo);
    }

    // QKV GEMM: [4096][3072] bf16, BK=64 swizzled, fully-resident grid
    {
        dim3 grid(M / 128, 3 * E_ / 128);
        gemm_qkv<<<grid, 256, 0, stream>>>(xb, wqkv, qb, kb, vb, qkv, M, 3 * E_, E_);
    }

    // global chunks (512, flash-partial, vectorized PV) + sparse rows (1024)
    attn_fused<<<512 + 1024, 256, 0, stream>>>(qkv, rnd, gaccp, gms, attn);

    // O GEMM -> fp32 out, 128x128 tile, fused global-row merge (no fin dispatch)
    {
        dim3 grid(M / 128, E_ / 128);
        gemm_o<<<grid, 256, 0, stream>>>(attn, wo, ob, gaccp, gms, out, M, E_, E_);
    }
}

// Round 12
// 161.601 us; speedup vs baseline: 1.0992x; 1.0259x over previous
//
#include <hip/hip_runtime.h>

#define B_  2
#define S_  2048
#define E_  1024
#define H_  16
#define D_  64
#define NGLOB 2
#define NRAND 3
#define WIN 3

typedef __bf16 bf16x8 __attribute__((ext_vector_type(8)));
typedef float  f32x4  __attribute__((ext_vector_type(4)));

__device__ __forceinline__ unsigned short f2bf(float f) {
    unsigned u = __builtin_bit_cast(unsigned, f);
    unsigned r = u + 0x7FFFu + ((u >> 16) & 1u);   // RNE
    return (unsigned short)(r >> 16);
}
__device__ __forceinline__ float bf2f(unsigned short u) {
    return __builtin_bit_cast(float, (unsigned)u << 16);
}

// async global->LDS 16B DMA. LDS dest is wave-uniform base + lane*16.
__device__ __forceinline__ void g2l16(const unsigned short* g, unsigned short* l) {
    __builtin_amdgcn_global_load_lds(
        (const __attribute__((address_space(1))) unsigned*)g,
        (__attribute__((address_space(3))) unsigned*)l, 16, 0, 0);
}

// ---------------- fused fp32 -> bf16 conversion for x + 4 weights ----------------
__global__ __launch_bounds__(256)
void convert_all(const float* __restrict__ x,  const float* __restrict__ qw,
                 const float* __restrict__ kw, const float* __restrict__ vw,
                 const float* __restrict__ ow,
                 unsigned short* __restrict__ xb, unsigned short* __restrict__ wqkv,
                 unsigned short* __restrict__ wo) {
    const int XN = (B_ * S_ * E_) / 4;      // 1048576
    const int WN = (E_ * E_) / 4;           // 262144
    int i = blockIdx.x * blockDim.x + threadIdx.x;
    int r, loc;
    if (i < XN) { r = 0; loc = i; }
    else        { int j = i - XN; r = 1 + (j >> 18); loc = j & (WN - 1); }
    const float* src = r == 0 ? x : r == 1 ? qw : r == 2 ? kw : r == 3 ? vw : ow;
    float4 f = ((const float4*)src)[loc];
    ushort4 u;
    u.x = f2bf(f.x); u.y = f2bf(f.y); u.z = f2bf(f.z); u.w = f2bf(f.w);
    ushort4* dst = r == 0 ? (ushort4*)xb : r == 4 ? (ushort4*)wo
                 : (ushort4*)wqkv + (size_t)(r - 1) * WN;
    dst[loc] = u;
}

// ---------------- QKV GEMM: BK=64, XOR-swizzled LDS (known-good) ------------------
__global__ __launch_bounds__(256, 3)
void gemm_qkv(const unsigned short* __restrict__ A,  // [M][K] bf16
              const unsigned short* __restrict__ W,  // [N][K] bf16
              const float* __restrict__ b0, const float* __restrict__ b1,
              const float* __restrict__ b2,
              unsigned short* __restrict__ Cb, int M, int N, int K) {
    __shared__ unsigned short sA[128 * 64];   // 16 KB
    __shared__ unsigned short sB[128 * 64];   // 16 KB
    const int t = threadIdx.x;
    const int lane = t & 63;
    const int wave = t >> 6;
    const int wm = wave >> 1, wn = wave & 1;
    const int lq = lane >> 4;
    const int lr = lane & 15;
    const int bm = blockIdx.x * 128;
    const int bn = blockIdx.y * 128;

    f32x4 acc[4][4] = {};

    for (int k0 = 0; k0 < K; k0 += 64) {
        const unsigned short* Abase = A + (size_t)bm * K + k0;
        const unsigned short* Wbase = W + (size_t)bn * K + k0;
        #pragma unroll
        for (int j = 0; j < 4; ++j) {             // 1024 chunks each
            int c = j * 256 + t;
            int row = c >> 3, cc = c & 7;
            int gcol = ((cc ^ (row & 7)) << 3);   // swizzled source col
            int dst = j * 2048 + wave * 512;      // wave-uniform elem offset
            g2l16(Abase + (size_t)row * K + gcol, sA + dst);
            g2l16(Wbase + (size_t)row * K + gcol, sB + dst);
        }
        __syncthreads();

        #pragma unroll
        for (int ks = 0; ks < 2; ++ks) {
            const int sw = (((ks << 2) + lq) ^ (lr & 7)) << 3;
            bf16x8 af[4], bfr[4];
            #pragma unroll
            for (int i = 0; i < 4; ++i)
                af[i] = *(const bf16x8*)&sA[(wm * 64 + i * 16 + lr) * 64 + sw];
            #pragma unroll
            for (int j = 0; j < 4; ++j)
                bfr[j] = *(const bf16x8*)&sB[(wn * 64 + j * 16 + lr) * 64 + sw];
            #pragma unroll
            for (int i = 0; i < 4; ++i)
                #pragma unroll
                for (int j = 0; j < 4; ++j)
                    acc[i][j] = __builtin_amdgcn_mfma_f32_16x16x32_bf16(af[i], bfr[j], acc[i][j], 0, 0, 0);
        }
        __syncthreads();
    }

    #pragma unroll
    for (int i = 0; i < 4; ++i) {
        int row0 = bm + wm * 64 + i * 16 + lq * 4;
        #pragma unroll
        for (int j = 0; j < 4; ++j) {
            int col = bn + wn * 64 + j * 16 + lr;
            const float* bp = col < E_ ? b0 : (col < 2 * E_ ? b1 : b2);
            float bv = bp[col & (E_ - 1)];
            #pragma unroll
            for (int r = 0; r < 4; ++r)
                Cb[(size_t)(row0 + r) * N + col] = f2bf(acc[i][j][r] + bv);
        }
    }
}

// ---------------- O GEMM: 128x128 tile, fused global-row merge --------------------
// Blocks with bm==0 / bm==2048 (sole consumers of attn rows {0,1} per batch)
// first compute the 8-chunk flash merge for their 2 global rows, write bf16 to
// attn, vmcnt(0)+barrier, then stage normally (self-read through own L2).
// 8 blocks per batch redundantly write IDENTICAL bytes — benign.
__global__ __launch_bounds__(256, 3)
void gemm_o(unsigned short* A,                      // attn (read + global-row write)
            const unsigned short* __restrict__ W,   // [N][K] bf16 (wo)
            const float* __restrict__ bias,
            const float* __restrict__ gaccp, const float* __restrict__ gms,
            float* __restrict__ Cf, int M, int N, int K) {
    __shared__ unsigned short sA[128 * 64];   // 16 KB
    __shared__ unsigned short sB[128 * 64];   // 16 KB
    const int t = threadIdx.x;
    const int lane = t & 63;
    const int wave = t >> 6;
    const int wm = wave >> 1, wn = wave & 1;
    const int lq = lane >> 4;
    const int lr = lane & 15;
    const int bm = blockIdx.x * 128;
    const int bn = blockIdx.y * 128;

    // ---- fused gattn_fin for this tile's global rows ----
    if (blockIdx.x == 0 || blockIdx.x == 16) {
        int b = blockIdx.x >> 4;
        #pragma unroll
        for (int r = 0; r < 8; ++r) {
            int oid = r * 256 + t;              // 0..2047 : i2*1024 + col
            int i2 = oid >> 10, col = oid & 1023;
            int h = col >> 6, d = col & 63;
            int tup = b * 32 + i2 * 16 + h;
            float Mx = -1e30f;
            #pragma unroll
            for (int c = 0; c < 8; ++c) Mx = fmaxf(Mx, gms[(tup * 8 + c) * 2]);
            float den = 0.f, num = 0.f;
            #pragma unroll
            for (int c = 0; c < 8; ++c) {
                float f = __expf(gms[(tup * 8 + c) * 2] - Mx);
                den += gms[(tup * 8 + c) * 2 + 1] * f;
                num += gaccp[(size_t)(tup * 8 + c) * D_ + d] * f;
            }
            A[(size_t)(b * S_ + i2) * E_ + col] = f2bf(num / den);
        }
        asm volatile("s_waitcnt vmcnt(0)" ::: "memory");
    }
    __syncthreads();

    f32x4 acc[4][4] = {};

    for (int k0 = 0; k0 < K; k0 += 64) {
        const unsigned short* Abase = A + (size_t)bm * K + k0;
        const unsigned short* Wbase = W + (size_t)bn * K + k0;
        #pragma unroll
        for (int j = 0; j < 4; ++j) {
            int c = j * 256 + t;
            int row = c >> 3, cc = c & 7;
            int gcol = ((cc ^ (row & 7)) << 3);
            int dst = j * 2048 + wave * 512;
            g2l16(Abase + (size_t)row * K + gcol, sA + dst);
            g2l16(Wbase + (size_t)row * K + gcol, sB + dst);
        }
        __syncthreads();

        #pragma unroll
        for (int ks = 0; ks < 2; ++ks) {
            const int sw = (((ks << 2) + lq) ^ (lr & 7)) << 3;
            bf16x8 af[4], bfr[4];
            #pragma unroll
            for (int i = 0; i < 4; ++i)
                af[i] = *(const bf16x8*)&sA[(wm * 64 + i * 16 + lr) * 64 + sw];
            #pragma unroll
            for (int j = 0; j < 4; ++j)
                bfr[j] = *(const bf16x8*)&sB[(wn * 64 + j * 16 + lr) * 64 + sw];
            #pragma unroll
            for (int i = 0; i < 4; ++i)
                #pragma unroll
                for (int j = 0; j < 4; ++j)
                    acc[i][j] = __builtin_amdgcn_mfma_f32_16x16x32_bf16(af[i], bfr[j], acc[i][j], 0, 0, 0);
        }
        __syncthreads();
    }

    #pragma unroll
    for (int i = 0; i < 4; ++i) {
        int row0 = bm + wm * 64 + i * 16 + lq * 4;
        #pragma unroll
        for (int j = 0; j < 4; ++j) {
            int col = bn + wn * 64 + j * 16 + lr;
            float bv = bias[col];
            #pragma unroll
            for (int r = 0; r < 4; ++r)
                Cf[(size_t)(row0 + r) * N + col] = acc[i][j][r] + bv;
        }
    }
}

// ---------------- fused: flash-style global chunks + sparse rows -----------------
// blocks [0,512) = (tuple x 256-key chunk) flash-partial with vectorized PV (R11).
// blocks [512,1536) = sparse rows, one wave per row. R12: sparse path is a SINGLE
// streaming pass with online softmax — K and V of each candidate load together
// (48 loads in one in-flight window), running (m, sum, o[16]) with group-uniform
// rescale. Removes the second gather round, the pr_s LDS round-trip, the divergent
// (l&3)==0 softmax block, and one barrier.
__global__ __launch_bounds__(256)
void attn_fused(const unsigned short* __restrict__ qkv,
                const int* __restrict__ rnd,
                float* __restrict__ gaccp, float* __restrict__ gms,
                unsigned short* __restrict__ attn) {
    const int NB = B_ * (S_ - 2);     // 4092
    int t = threadIdx.x;

    if (blockIdx.x < 512) {
        // ---- one (tuple, key-chunk) per block ----
        int tup = blockIdx.x >> 3, seg = blockIdx.x & 7;
        int b = tup >> 5, i = (tup >> 4) & 1, h = tup & 15;
        int w = t >> 6, l = t & 63;
        __shared__ float ps[256];
        __shared__ float red[4];
        __shared__ float ov[4][D_];

        // q chunk for this lane: 8 bf16 at chunk (l&7) of head slice
        const bf16x8* qp = (const bf16x8*)(qkv + (size_t)(b * S_ + i) * 3072 + h * D_);
        bf16x8 qv = qp[l & 7];
        float qreg[8];
        #pragma unroll
        for (int j = 0; j < 8; ++j) qreg[j] = (float)qv[j];

        // scores: wave w covers keys [seg*256 + w*64, +64), 8 keys/iter
        const int key0 = seg * 256 + w * 64;
        float sc[8];
        #pragma unroll
        for (int it = 0; it < 8; ++it) {
            int key = key0 + it * 8 + (l >> 3);
            const bf16x8* kp = (const bf16x8*)(qkv + (size_t)(b * S_ + key) * 3072 + E_ + h * D_);
            bf16x8 kv = kp[l & 7];
            float s = 0.f;
            #pragma unroll
            for (int j = 0; j < 8; ++j) s += qreg[j] * (float)kv[j];
            s += __shfl_xor(s, 1);
            s += __shfl_xor(s, 2);
            s += __shfl_xor(s, 4);
            sc[it] = s * 0.125f;
        }
        #pragma unroll
        for (int it = 0; it < 8; ++it)
            if ((l & 7) == 0) ps[w * 64 + it * 8 + (l >> 3)] = sc[it];
        __syncthreads();

        // chunk-local softmax partials
        float v = ps[t];
        float m = v;
        #pragma unroll
        for (int o = 32; o; o >>= 1) m = fmaxf(m, __shfl_xor(m, o));
        if (l == 0) red[w] = m;
        __syncthreads();
        m = fmaxf(fmaxf(red[0], red[1]), fmaxf(red[2], red[3]));
        float e = __expf(v - m);
        float sum = e;
        #pragma unroll
        for (int o = 32; o; o >>= 1) sum += __shfl_xor(sum, o);
        __syncthreads();
        if (l == 0) red[w] = sum;
        ps[t] = e;                       // unnormalized probs
        __syncthreads();
        if (t == 0) {
            float stot = red[0] + red[1] + red[2] + red[3];
            gms[(tup * 8 + seg) * 2]     = m;
            gms[(tup * 8 + seg) * 2 + 1] = stot;
        }

        // PV over this chunk, vectorized: wave w keys [key0,+64);
        // lane = (ksb = l>>3 key-sub, dg = l&7 dim-group of 8 dims)
        const int ksb = l >> 3, dg = l & 7;
        float o[8] = {};
        #pragma unroll
        for (int kk = 0; kk < 8; ++kk) {
            int key = key0 + kk * 8 + ksb;
            const bf16x8* vp = (const bf16x8*)(qkv + (size_t)(b * S_ + key) * 3072
                                               + 2 * E_ + h * D_ + dg * 8);
            bf16x8 vv = *vp;
            float p = ps[w * 64 + kk * 8 + ksb];
            #pragma unroll
            for (int e2 = 0; e2 < 8; ++e2) o[e2] += p * (float)vv[e2];
        }
        #pragma unroll
        for (int mask = 8; mask <= 32; mask <<= 1)
            #pragma unroll
            for (int e2 = 0; e2 < 8; ++e2) o[e2] += __shfl_xor(o[e2], mask);
        if (ksb == 0)
            #pragma unroll
            for (int e2 = 0; e2 < 8; ++e2) ov[w][dg * 8 + e2] = o[e2];
        __syncthreads();
        if (w == 0)
            gaccp[((size_t)tup * 8 + seg) * D_ + l] =
                ov[0][l] + ov[1][l] + ov[2][l] + ov[3][l];
        return;
    }

    // ---- sparse rows: one wave per row, single streaming pass (R12) ----
    int bb = blockIdx.x - 512;                        // [0,1024)
    int bidx = (bb & 7) * 128 + (bb >> 3);            // XCD swizzle
    int w = t >> 6, l = t & 63;
    int row = bidx * 4 + w;
    bool valid = row < NB;
    int b = row / (S_ - 2);
    int i = row % (S_ - 2) + 2;
    if (!valid) { b = 0; i = 2; }

    __shared__ int cols_s[4][12];
    __shared__ int ncol_sh[4];

    const bf16x8* qp = (const bf16x8*)(qkv + (size_t)(b * S_ + i) * 3072);
    bf16x8 q0 = qp[l * 2], q1 = qp[l * 2 + 1];
    float qreg[16];
    #pragma unroll
    for (int j = 0; j < 8; ++j) { qreg[j] = (float)q0[j]; qreg[8 + j] = (float)q1[j]; }

    if (l == 0) {
        int* cols = cols_s[w];
        int n = 0;
        cols[n++] = 0; cols[n++] = 1;
        int lo = i - WIN; if (lo < NGLOB) lo = NGLOB;
        int hi = i + WIN; if (hi > S_ - 1) hi = S_ - 1;
        for (int j = lo; j <= hi; ++j) cols[n++] = j;
        for (int r = 0; r < NRAND; ++r) {
            int c = rnd[i * NRAND + r];
            bool dup = false;
            for (int q = 0; q < n; ++q) dup = dup || (cols[q] == c);
            if (!dup) cols[n++] = c;
        }
        ncol_sh[w] = n;
        for (int q = n; q < 12; ++q) cols[q] = 0;
    }
    __syncthreads();
    const int n = ncol_sh[w];

    // streaming online-softmax: K and V of each candidate load together;
    // running (mM, ssum, o[16]) with 4-lane-group-uniform rescale.
    float mM = -1e30f, ssum = 0.f;
    float o[16] = {};
    #pragma unroll
    for (int c = 0; c < 12; ++c) {
        const unsigned short* base = qkv + (size_t)(b * S_ + cols_s[w][c]) * 3072 + E_;
        const bf16x8* kp = (const bf16x8*)base;
        bf16x8 k0 = kp[l * 2], k1 = kp[l * 2 + 1];
        const bf16x8* vp = (const bf16x8*)(base + E_);
        bf16x8 v0 = vp[l * 2], v1 = vp[l * 2 + 1];
        float s = 0.f;
        #pragma unroll
        for (int j = 0; j < 8; ++j) s += qreg[j] * (float)k0[j] + qreg[8 + j] * (float)k1[j];
        s += __shfl_xor(s, 1);
        s += __shfl_xor(s, 2);
        s = (c < n) ? s * 0.125f : -1e30f;
        if (s > mM) {                         // group-uniform (s identical in 4-lane group)
            float r = __expf(mM - s);
            ssum *= r;
            #pragma unroll
            for (int j = 0; j < 16; ++j) o[j] *= r;
            mM = s;
        }
        float e = __expf(s - mM);
        ssum += e;
        #pragma unroll
        for (int j = 0; j < 8; ++j) { o[j] += e * (float)v0[j]; o[8 + j] += e * (float)v1[j]; }
    }
    float inv = 1.f / ssum;
    #pragma unroll
    for (int j = 0; j < 16; ++j) o[j] *= inv;

    if (valid) {
        ushort4 u0, u1, u2, u3;
        u0.x = f2bf(o[0]);  u0.y = f2bf(o[1]);  u0.z = f2bf(o[2]);  u0.w = f2bf(o[3]);
        u1.x = f2bf(o[4]);  u1.y = f2bf(o[5]);  u1.z = f2bf(o[6]);  u1.w = f2bf(o[7]);
        u2.x = f2bf(o[8]);  u2.y = f2bf(o[9]);  u2.z = f2bf(o[10]); u2.w = f2bf(o[11]);
        u3.x = f2bf(o[12]); u3.y = f2bf(o[13]); u3.z = f2bf(o[14]); u3.w = f2bf(o[15]);
        ushort4* op = (ushort4*)(attn + (size_t)(b * S_ + i) * E_ + l * 16);
        op[0] = u0; op[1] = u1; op[2] = u2; op[3] = u3;
    }
}

extern "C" void kernel_launch(void* const* d_in, const int* in_sizes, int n_in,
                              void* d_out, int out_size, void* d_ws, size_t ws_size,
                              hipStream_t stream) {
    const float* x   = (const float*)d_in[0];
    const int*   rnd = (const int*)d_in[1];
    const float* qw  = (const float*)d_in[2];
    const float* qb  = (const float*)d_in[3];
    const float* kw  = (const float*)d_in[4];
    const float* kb  = (const float*)d_in[5];
    const float* vw  = (const float*)d_in[6];
    const float* vb  = (const float*)d_in[7];
    const float* ow  = (const float*)d_in[8];
    const float* ob  = (const float*)d_in[9];
    float* out = (float*)d_out;

    char* ws = (char*)d_ws;
    unsigned short* xb    = (unsigned short*)(ws);                       // 8 MB (dead after QKV GEMM)
    unsigned short* wqkv  = (unsigned short*)(ws + 8388608);             // 6 MB
    unsigned short* wo    = (unsigned short*)(ws + 14680064);            // 2 MB
    unsigned short* qkv   = (unsigned short*)(ws + 16777216);            // 24 MB
    unsigned short* attn  = (unsigned short*)(ws + 41943040);            // 8 MB
    float*          gaccp = (float*)(ws);                                // 128 KB (overlaps dead xb)
    float*          gms   = (float*)(ws + 131072);                       // 4 KB

    const int M = B_ * S_;   // 4096

    {
        int total4 = (M * E_ + 4 * E_ * E_) / 4;
        convert_all<<<total4 / 256, 256, 0, stream>>>(x, qw, kw, vw, ow, xb, wqkv, wo);
    }

    // QKV GEMM: [4096][3072] bf16, BK=64 swizzled, fully-resident grid
    {
        dim3 grid(M / 128, 3 * E_ / 128);
        gemm_qkv<<<grid, 256, 0, stream>>>(xb, wqkv, qb, kb, vb, qkv, M, 3 * E_, E_);
    }

    // global chunks (512, flash-partial, vectorized PV) + sparse rows (1024, streaming)
    attn_fused<<<512 + 1024, 256, 0, stream>>>(qkv, rnd, gaccp, gms, attn);

    // O GEMM -> fp32 out, 128x128 tile, fused global-row merge (no fin dispatch)
    {
        dim3 grid(M / 128, E_ / 128);
        gemm_o<<<grid, 256, 0, stream>>>(attn, wo, ob, gaccp, gms, out, M, E_, E_);
    }
}

// Round 13
// 159.815 us; speedup vs baseline: 1.1115x; 1.0112x over previous
//
#include <hip/hip_runtime.h>

#define B_  2
#define S_  2048
#define E_  1024
#define H_  16
#define D_  64
#define NGLOB 2
#define NRAND 3
#define WIN 3

typedef __bf16 bf16x8 __attribute__((ext_vector_type(8)));
typedef float  f32x4  __attribute__((ext_vector_type(4)));

__device__ __forceinline__ unsigned short f2bf(float f) {
    unsigned u = __builtin_bit_cast(unsigned, f);
    unsigned r = u + 0x7FFFu + ((u >> 16) & 1u);   // RNE
    return (unsigned short)(r >> 16);
}
__device__ __forceinline__ float bf2f(unsigned short u) {
    return __builtin_bit_cast(float, (unsigned)u << 16);
}

// async global->LDS 16B DMA. LDS dest is wave-uniform base + lane*16.
__device__ __forceinline__ void g2l16(const unsigned short* g, unsigned short* l) {
    __builtin_amdgcn_global_load_lds(
        (const __attribute__((address_space(1))) unsigned*)g,
        (__attribute__((address_space(3))) unsigned*)l, 16, 0, 0);
}

// ---------------- fused fp32 -> bf16 conversion for x + 4 weights ----------------
__global__ __launch_bounds__(256)
void convert_all(const float* __restrict__ x,  const float* __restrict__ qw,
                 const float* __restrict__ kw, const float* __restrict__ vw,
                 const float* __restrict__ ow,
                 unsigned short* __restrict__ xb, unsigned short* __restrict__ wqkv,
                 unsigned short* __restrict__ wo) {
    const int XN = (B_ * S_ * E_) / 4;      // 1048576
    const int WN = (E_ * E_) / 4;           // 262144
    int i = blockIdx.x * blockDim.x + threadIdx.x;
    int r, loc;
    if (i < XN) { r = 0; loc = i; }
    else        { int j = i - XN; r = 1 + (j >> 18); loc = j & (WN - 1); }
    const float* src = r == 0 ? x : r == 1 ? qw : r == 2 ? kw : r == 3 ? vw : ow;
    float4 f = ((const float4*)src)[loc];
    ushort4 u;
    u.x = f2bf(f.x); u.y = f2bf(f.y); u.z = f2bf(f.z); u.w = f2bf(f.w);
    ushort4* dst = r == 0 ? (ushort4*)xb : r == 4 ? (ushort4*)wo
                 : (ushort4*)wqkv + (size_t)(r - 1) * WN;
    dst[loc] = u;
}

// ---------------- QKV GEMM: BK=64, XOR-swizzled LDS (known-good) ------------------
__global__ __launch_bounds__(256, 3)
void gemm_qkv(const unsigned short* __restrict__ A,  // [M][K] bf16
              const unsigned short* __restrict__ W,  // [N][K] bf16
              const float* __restrict__ b0, const float* __restrict__ b1,
              const float* __restrict__ b2,
              unsigned short* __restrict__ Cb, int M, int N, int K) {
    __shared__ unsigned short sA[128 * 64];   // 16 KB
    __shared__ unsigned short sB[128 * 64];   // 16 KB
    const int t = threadIdx.x;
    const int lane = t & 63;
    const int wave = t >> 6;
    const int wm = wave >> 1, wn = wave & 1;
    const int lq = lane >> 4;
    const int lr = lane & 15;
    const int bm = blockIdx.x * 128;
    const int bn = blockIdx.y * 128;

    f32x4 acc[4][4] = {};

    for (int k0 = 0; k0 < K; k0 += 64) {
        const unsigned short* Abase = A + (size_t)bm * K + k0;
        const unsigned short* Wbase = W + (size_t)bn * K + k0;
        #pragma unroll
        for (int j = 0; j < 4; ++j) {             // 1024 chunks each
            int c = j * 256 + t;
            int row = c >> 3, cc = c & 7;
            int gcol = ((cc ^ (row & 7)) << 3);   // swizzled source col
            int dst = j * 2048 + wave * 512;      // wave-uniform elem offset
            g2l16(Abase + (size_t)row * K + gcol, sA + dst);
            g2l16(Wbase + (size_t)row * K + gcol, sB + dst);
        }
        __syncthreads();

        #pragma unroll
        for (int ks = 0; ks < 2; ++ks) {
            const int sw = (((ks << 2) + lq) ^ (lr & 7)) << 3;
            bf16x8 af[4], bfr[4];
            #pragma unroll
            for (int i = 0; i < 4; ++i)
                af[i] = *(const bf16x8*)&sA[(wm * 64 + i * 16 + lr) * 64 + sw];
            #pragma unroll
            for (int j = 0; j < 4; ++j)
                bfr[j] = *(const bf16x8*)&sB[(wn * 64 + j * 16 + lr) * 64 + sw];
            #pragma unroll
            for (int i = 0; i < 4; ++i)
                #pragma unroll
                for (int j = 0; j < 4; ++j)
                    acc[i][j] = __builtin_amdgcn_mfma_f32_16x16x32_bf16(af[i], bfr[j], acc[i][j], 0, 0, 0);
        }
        __syncthreads();
    }

    #pragma unroll
    for (int i = 0; i < 4; ++i) {
        int row0 = bm + wm * 64 + i * 16 + lq * 4;
        #pragma unroll
        for (int j = 0; j < 4; ++j) {
            int col = bn + wn * 64 + j * 16 + lr;
            const float* bp = col < E_ ? b0 : (col < 2 * E_ ? b1 : b2);
            float bv = bp[col & (E_ - 1)];
            #pragma unroll
            for (int r = 0; r < 4; ++r)
                Cb[(size_t)(row0 + r) * N + col] = f2bf(acc[i][j][r] + bv);
        }
    }
}

// ---------------- O GEMM: 128x128 tile, fused global-row merge --------------------
// Blocks with bm==0 / bm==2048 (sole consumers of attn rows {0,1} per batch)
// first compute the 8-chunk flash merge for their 2 global rows, write bf16 to
// attn, vmcnt(0)+barrier, then stage normally (self-read through own L2).
// 8 blocks per batch redundantly write IDENTICAL bytes — benign.
__global__ __launch_bounds__(256, 3)
void gemm_o(unsigned short* A,                      // attn (read + global-row write)
            const unsigned short* __restrict__ W,   // [N][K] bf16 (wo)
            const float* __restrict__ bias,
            const float* __restrict__ gaccp, const float* __restrict__ gms,
            float* __restrict__ Cf, int M, int N, int K) {
    __shared__ unsigned short sA[128 * 64];   // 16 KB
    __shared__ unsigned short sB[128 * 64];   // 16 KB
    const int t = threadIdx.x;
    const int lane = t & 63;
    const int wave = t >> 6;
    const int wm = wave >> 1, wn = wave & 1;
    const int lq = lane >> 4;
    const int lr = lane & 15;
    const int bm = blockIdx.x * 128;
    const int bn = blockIdx.y * 128;

    // ---- fused gattn_fin for this tile's global rows ----
    if (blockIdx.x == 0 || blockIdx.x == 16) {
        int b = blockIdx.x >> 4;
        #pragma unroll
        for (int r = 0; r < 8; ++r) {
            int oid = r * 256 + t;              // 0..2047 : i2*1024 + col
            int i2 = oid >> 10, col = oid & 1023;
            int h = col >> 6, d = col & 63;
            int tup = b * 32 + i2 * 16 + h;
            float Mx = -1e30f;
            #pragma unroll
            for (int c = 0; c < 8; ++c) Mx = fmaxf(Mx, gms[(tup * 8 + c) * 2]);
            float den = 0.f, num = 0.f;
            #pragma unroll
            for (int c = 0; c < 8; ++c) {
                float f = __expf(gms[(tup * 8 + c) * 2] - Mx);
                den += gms[(tup * 8 + c) * 2 + 1] * f;
                num += gaccp[(size_t)(tup * 8 + c) * D_ + d] * f;
            }
            A[(size_t)(b * S_ + i2) * E_ + col] = f2bf(num / den);
        }
        asm volatile("s_waitcnt vmcnt(0)" ::: "memory");
    }
    __syncthreads();

    f32x4 acc[4][4] = {};

    for (int k0 = 0; k0 < K; k0 += 64) {
        const unsigned short* Abase = A + (size_t)bm * K + k0;
        const unsigned short* Wbase = W + (size_t)bn * K + k0;
        #pragma unroll
        for (int j = 0; j < 4; ++j) {
            int c = j * 256 + t;
            int row = c >> 3, cc = c & 7;
            int gcol = ((cc ^ (row & 7)) << 3);
            int dst = j * 2048 + wave * 512;
            g2l16(Abase + (size_t)row * K + gcol, sA + dst);
            g2l16(Wbase + (size_t)row * K + gcol, sB + dst);
        }
        __syncthreads();

        #pragma unroll
        for (int ks = 0; ks < 2; ++ks) {
            const int sw = (((ks << 2) + lq) ^ (lr & 7)) << 3;
            bf16x8 af[4], bfr[4];
            #pragma unroll
            for (int i = 0; i < 4; ++i)
                af[i] = *(const bf16x8*)&sA[(wm * 64 + i * 16 + lr) * 64 + sw];
            #pragma unroll
            for (int j = 0; j < 4; ++j)
                bfr[j] = *(const bf16x8*)&sB[(wn * 64 + j * 16 + lr) * 64 + sw];
            #pragma unroll
            for (int i = 0; i < 4; ++i)
                #pragma unroll
                for (int j = 0; j < 4; ++j)
                    acc[i][j] = __builtin_amdgcn_mfma_f32_16x16x32_bf16(af[i], bfr[j], acc[i][j], 0, 0, 0);
        }
        __syncthreads();
    }

    #pragma unroll
    for (int i = 0; i < 4; ++i) {
        int row0 = bm + wm * 64 + i * 16 + lq * 4;
        #pragma unroll
        for (int j = 0; j < 4; ++j) {
            int col = bn + wn * 64 + j * 16 + lr;
            float bv = bias[col];
            #pragma unroll
            for (int r = 0; r < 4; ++r)
                Cf[(size_t)(row0 + r) * N + col] = acc[i][j][r] + bv;
        }
    }
}

// ---------------- fused: streaming global chunks + streaming sparse rows ---------
// R13: global path now mirrors R12's sparse streaming. Each wave processes its 64
// keys in ONE pass: per iter load K-chunk AND V-chunk together (16 loads, one
// in-flight window), 3-shfl score reduce, 3-shfl wave-max, online (mM, sum, o[8])
// rescale. Then one key-sub shfl reduction, ONE barrier, 4-wave flash merge to
// gms/gaccp (same semantics as before; gemm_o merge unchanged). Removes ps[256]
// LDS round-trip, 2 of 3 barriers, and one full gather-latency round per block.
__global__ __launch_bounds__(256)
void attn_fused(const unsigned short* __restrict__ qkv,
                const int* __restrict__ rnd,
                float* __restrict__ gaccp, float* __restrict__ gms,
                unsigned short* __restrict__ attn) {
    const int NB = B_ * (S_ - 2);     // 4092
    int t = threadIdx.x;

    if (blockIdx.x < 512) {
        // ---- one (tuple, key-chunk) per block, single streaming pass ----
        int tup = blockIdx.x >> 3, seg = blockIdx.x & 7;
        int b = tup >> 5, i = (tup >> 4) & 1, h = tup & 15;
        int w = t >> 6, l = t & 63;
        __shared__ float redm[4], reds[4];
        __shared__ float ov[4][D_];

        // q chunk for this lane: 8 bf16 dims (l&7)*8.. of the head slice
        const bf16x8* qp = (const bf16x8*)(qkv + (size_t)(b * S_ + i) * 3072 + h * D_);
        bf16x8 qv = qp[l & 7];
        float qreg[8];
        #pragma unroll
        for (int j = 0; j < 8; ++j) qreg[j] = (float)qv[j];

        // lane = (ksb key-sub, dg dim-group); wave w covers keys [key0, +64)
        const int key0 = seg * 256 + w * 64;
        const int ksb = l >> 3, dg = l & 7;
        float mM = -1e30f, ssum = 0.f;
        float o[8] = {};
        #pragma unroll
        for (int it = 0; it < 8; ++it) {
            int key = key0 + it * 8 + ksb;
            const unsigned short* kr =
                qkv + (size_t)(b * S_ + key) * 3072 + E_ + h * D_ + dg * 8;
            bf16x8 kv = *(const bf16x8*)kr;          // K chunk
            bf16x8 vv = *(const bf16x8*)(kr + E_);   // V chunk, same key/dims
            float s = 0.f;
            #pragma unroll
            for (int j = 0; j < 8; ++j) s += qreg[j] * (float)kv[j];
            s += __shfl_xor(s, 1);
            s += __shfl_xor(s, 2);
            s += __shfl_xor(s, 4);
            s *= 0.125f;                             // score for key it*8+ksb (all dg lanes)
            float m_it = s;
            m_it = fmaxf(m_it, __shfl_xor(m_it, 8));
            m_it = fmaxf(m_it, __shfl_xor(m_it, 16));
            m_it = fmaxf(m_it, __shfl_xor(m_it, 32));
            if (m_it > mM) {                         // wave-uniform
                float r = __expf(mM - m_it);
                ssum *= r;
                #pragma unroll
                for (int e2 = 0; e2 < 8; ++e2) o[e2] *= r;
                mM = m_it;
            }
            float e = __expf(s - mM);
            ssum += e;
            #pragma unroll
            for (int e2 = 0; e2 < 8; ++e2) o[e2] += e * (float)vv[e2];
        }
        // reduce over key-subs (masks vary ksb, keep dg)
        #pragma unroll
        for (int mask = 8; mask <= 32; mask <<= 1) {
            ssum += __shfl_xor(ssum, mask);
            #pragma unroll
            for (int e2 = 0; e2 < 8; ++e2) o[e2] += __shfl_xor(o[e2], mask);
        }
        if (l == 0) { redm[w] = mM; reds[w] = ssum; }
        if (ksb == 0)
            #pragma unroll
            for (int e2 = 0; e2 < 8; ++e2) ov[w][dg * 8 + e2] = o[e2];
        __syncthreads();
        if (w == 0) {
            float M = fmaxf(fmaxf(redm[0], redm[1]), fmaxf(redm[2], redm[3]));
            float f0 = __expf(redm[0] - M), f1 = __expf(redm[1] - M);
            float f2 = __expf(redm[2] - M), f3 = __expf(redm[3] - M);
            gaccp[((size_t)tup * 8 + seg) * D_ + l] =
                ov[0][l] * f0 + ov[1][l] * f1 + ov[2][l] * f2 + ov[3][l] * f3;
            if (l == 0) {
                gms[(tup * 8 + seg) * 2]     = M;
                gms[(tup * 8 + seg) * 2 + 1] =
                    reds[0] * f0 + reds[1] * f1 + reds[2] * f2 + reds[3] * f3;
            }
        }
        return;
    }

    // ---- sparse rows: one wave per row, single streaming pass (R12) ----
    int bb = blockIdx.x - 512;                        // [0,1024)
    int bidx = (bb & 7) * 128 + (bb >> 3);            // XCD swizzle
    int w = t >> 6, l = t & 63;
    int row = bidx * 4 + w;
    bool valid = row < NB;
    int b = row / (S_ - 2);
    int i = row % (S_ - 2) + 2;
    if (!valid) { b = 0; i = 2; }

    __shared__ int cols_s[4][12];
    __shared__ int ncol_sh[4];

    const bf16x8* qp = (const bf16x8*)(qkv + (size_t)(b * S_ + i) * 3072);
    bf16x8 q0 = qp[l * 2], q1 = qp[l * 2 + 1];
    float qreg[16];
    #pragma unroll
    for (int j = 0; j < 8; ++j) { qreg[j] = (float)q0[j]; qreg[8 + j] = (float)q1[j]; }

    if (l == 0) {
        int* cols = cols_s[w];
        int n = 0;
        cols[n++] = 0; cols[n++] = 1;
        int lo = i - WIN; if (lo < NGLOB) lo = NGLOB;
        int hi = i + WIN; if (hi > S_ - 1) hi = S_ - 1;
        for (int j = lo; j <= hi; ++j) cols[n++] = j;
        for (int r = 0; r < NRAND; ++r) {
            int c = rnd[i * NRAND + r];
            bool dup = false;
            for (int q = 0; q < n; ++q) dup = dup || (cols[q] == c);
            if (!dup) cols[n++] = c;
        }
        ncol_sh[w] = n;
        for (int q = n; q < 12; ++q) cols[q] = 0;
    }
    __syncthreads();
    const int n = ncol_sh[w];

    // streaming online-softmax: K and V of each candidate load together;
    // running (mM, ssum, o[16]) with 4-lane-group-uniform rescale.
    float mM = -1e30f, ssum = 0.f;
    float o[16] = {};
    #pragma unroll
    for (int c = 0; c < 12; ++c) {
        const unsigned short* base = qkv + (size_t)(b * S_ + cols_s[w][c]) * 3072 + E_;
        const bf16x8* kp = (const bf16x8*)base;
        bf16x8 k0 = kp[l * 2], k1 = kp[l * 2 + 1];
        const bf16x8* vp = (const bf16x8*)(base + E_);
        bf16x8 v0 = vp[l * 2], v1 = vp[l * 2 + 1];
        float s = 0.f;
        #pragma unroll
        for (int j = 0; j < 8; ++j) s += qreg[j] * (float)k0[j] + qreg[8 + j] * (float)k1[j];
        s += __shfl_xor(s, 1);
        s += __shfl_xor(s, 2);
        s = (c < n) ? s * 0.125f : -1e30f;
        if (s > mM) {                         // group-uniform (s identical in 4-lane group)
            float r = __expf(mM - s);
            ssum *= r;
            #pragma unroll
            for (int j = 0; j < 16; ++j) o[j] *= r;
            mM = s;
        }
        float e = __expf(s - mM);
        ssum += e;
        #pragma unroll
        for (int j = 0; j < 8; ++j) { o[j] += e * (float)v0[j]; o[8 + j] += e * (float)v1[j]; }
    }
    float inv = 1.f / ssum;
    #pragma unroll
    for (int j = 0; j < 16; ++j) o[j] *= inv;

    if (valid) {
        ushort4 u0, u1, u2, u3;
        u0.x = f2bf(o[0]);  u0.y = f2bf(o[1]);  u0.z = f2bf(o[2]);  u0.w = f2bf(o[3]);
        u1.x = f2bf(o[4]);  u1.y = f2bf(o[5]);  u1.z = f2bf(o[6]);  u1.w = f2bf(o[7]);
        u2.x = f2bf(o[8]);  u2.y = f2bf(o[9]);  u2.z = f2bf(o[10]); u2.w = f2bf(o[11]);
        u3.x = f2bf(o[12]); u3.y = f2bf(o[13]); u3.z = f2bf(o[14]); u3.w = f2bf(o[15]);
        ushort4* op = (ushort4*)(attn + (size_t)(b * S_ + i) * E_ + l * 16);
        op[0] = u0; op[1] = u1; op[2] = u2; op[3] = u3;
    }
}

extern "C" void kernel_launch(void* const* d_in, const int* in_sizes, int n_in,
                              void* d_out, int out_size, void* d_ws, size_t ws_size,
                              hipStream_t stream) {
    const float* x   = (const float*)d_in[0];
    const int*   rnd = (const int*)d_in[1];
    const float* qw  = (const float*)d_in[2];
    const float* qb  = (const float*)d_in[3];
    const float* kw  = (const float*)d_in[4];
    const float* kb  = (const float*)d_in[5];
    const float* vw  = (const float*)d_in[6];
    const float* vb  = (const float*)d_in[7];
    const float* ow  = (const float*)d_in[8];
    const float* ob  = (const float*)d_in[9];
    float* out = (float*)d_out;

    char* ws = (char*)d_ws;
    unsigned short* xb    = (unsigned short*)(ws);                       // 8 MB (dead after QKV GEMM)
    unsigned short* wqkv  = (unsigned short*)(ws + 8388608);             // 6 MB
    unsigned short* wo    = (unsigned short*)(ws + 14680064);            // 2 MB
    unsigned short* qkv   = (unsigned short*)(ws + 16777216);            // 24 MB
    unsigned short* attn  = (unsigned short*)(ws + 41943040);            // 8 MB
    float*          gaccp = (float*)(ws);                                // 128 KB (overlaps dead xb)
    float*          gms   = (float*)(ws + 131072);                       // 4 KB

    const int M = B_ * S_;   // 4096

    {
        int total4 = (M * E_ + 4 * E_ * E_) / 4;
        convert_all<<<total4 / 256, 256, 0, stream>>>(x, qw, kw, vw, ow, xb, wqkv, wo);
    }

    // QKV GEMM: [4096][3072] bf16, BK=64 swizzled, fully-resident grid
    {
        dim3 grid(M / 128, 3 * E_ / 128);
        gemm_qkv<<<grid, 256, 0, stream>>>(xb, wqkv, qb, kb, vb, qkv, M, 3 * E_, E_);
    }

    // global chunks (512, streaming flash) + sparse rows (1024, streaming)
    attn_fused<<<512 + 1024, 256, 0, stream>>>(qkv, rnd, gaccp, gms, attn);

    // O GEMM -> fp32 out, 128x128 tile, fused global-row merge (no fin dispatch)
    {
        dim3 grid(M / 128, E_ / 128);
        gemm_o<<<grid, 256, 0, stream>>>(attn, wo, ob, gaccp, gms, out, M, E_, E_);
    }
}